// Round 1
// baseline (685.956 us; speedup 1.0000x reference)
//
#include <hip/hip_runtime.h>
#include <math.h>

#define DF 128

// ---------------- CSR build ----------------

__global__ void hist_k(const int* __restrict__ dst, const float* __restrict__ ew,
                       int* __restrict__ cnt, float* __restrict__ sumew, int E) {
    int i = blockIdx.x * blockDim.x + threadIdx.x;
    if (i < E) {
        int d = dst[i];
        atomicAdd(&cnt[d], 1);
        atomicAdd(&sumew[d], ew[i]);
    }
}

// single-block scan: 256 threads, each owns a contiguous chunk
__global__ void scan_k(const int* __restrict__ cnt, int* __restrict__ rowptr,
                       int* __restrict__ cursor, int N) {
    const int T = 256;
    int t = threadIdx.x;
    int chunk = (N + T - 1) / T;
    int lo = t * chunk;
    int hi = min(lo + chunk, N);
    int s = 0;
    for (int i = lo; i < hi; ++i) s += cnt[i];
    __shared__ int sm[T];
    sm[t] = s;
    __syncthreads();
    for (int off = 1; off < T; off <<= 1) {
        int v = (t >= off) ? sm[t - off] : 0;
        __syncthreads();
        sm[t] += v;
        __syncthreads();
    }
    int run = sm[t] - s;  // exclusive prefix
    for (int i = lo; i < hi; ++i) {
        rowptr[i] = run;
        cursor[i] = run;
        run += cnt[i];
    }
    if (t == T - 1) rowptr[N] = sm[T - 1];
}

__global__ void fill_k(const int* __restrict__ src, const int* __restrict__ dst,
                       const float* __restrict__ ew, int* __restrict__ cursor,
                       int* __restrict__ adj_src, float* __restrict__ adj_w, int E) {
    int i = blockIdx.x * blockDim.x + threadIdx.x;
    if (i < E) {
        int p = atomicAdd(&cursor[dst[i]], 1);
        adj_src[p] = src[i];
        adj_w[p] = ew[i];
    }
}

// ---------------- aggregation (pull, one wave per node) ----------------

template <int SELF>
__global__ void agg_k(const float* __restrict__ xin, const int* __restrict__ rowptr,
                      const int* __restrict__ adj_src, const float* __restrict__ adj_w,
                      float* __restrict__ agg, int N) {
    int wid = (blockIdx.x * blockDim.x + threadIdx.x) >> 6;
    int lane = threadIdx.x & 63;
    if (wid >= N) return;
    int lo = rowptr[wid], hi = rowptr[wid + 1];
    float a0 = 0.f, a1 = 0.f;
    if (SELF) {  // self loop with weight 1
        a0 = xin[(size_t)wid * DF + lane];
        a1 = xin[(size_t)wid * DF + 64 + lane];
    }
    for (int p = lo; p < hi; ++p) {
        int s = adj_src[p];
        float w = adj_w[p];
        a0 += w * xin[(size_t)s * DF + lane];
        a1 += w * xin[(size_t)s * DF + 64 + lane];
    }
    float inv = SELF ? 1.0f / (float)(hi - lo + 1)
                     : 1.0f / fmaxf((float)(hi - lo), 1.0f);
    agg[(size_t)wid * DF + lane] = a0 * inv;
    agg[(size_t)wid * DF + 64 + lane] = a1 * inv;
}

// ---------------- GEMMs: one wave per node, W in LDS ----------------

__global__ __launch_bounds__(256) void gemm1_k(
    const float* __restrict__ agg, const float* __restrict__ W,
    const float* __restrict__ bl, const float* __restrict__ sumew,
    const int* __restrict__ rowptr, float* __restrict__ x1, int N) {
    __shared__ float Ws[DF][DF];
    {
        const float4* Wv = (const float4*)W;
        float4* Sv = (float4*)&Ws[0][0];
        for (int idx = threadIdx.x; idx < DF * DF / 4; idx += blockDim.x) Sv[idx] = Wv[idx];
    }
    __syncthreads();
    int w = threadIdx.x >> 6, lane = threadIdx.x & 63;
    float b0 = bl[lane], b1 = bl[64 + lane];
    for (int i = blockIdx.x * 4 + w; i < N; i += gridDim.x * 4) {
        float r0 = agg[(size_t)i * DF + lane];
        float r1 = agg[(size_t)i * DF + 64 + lane];
        float c0 = 0.f, c1 = 0.f;
#pragma unroll 16
        for (int k = 0; k < 64; ++k) {
            float a = __shfl(r0, k);
            c0 += a * Ws[k][lane];
            c1 += a * Ws[k][64 + lane];
        }
#pragma unroll 16
        for (int k = 0; k < 64; ++k) {
            float a = __shfl(r1, k);
            c0 += a * Ws[64 + k][lane];
            c1 += a * Ws[64 + k][64 + lane];
        }
        int deg = rowptr[i + 1] - rowptr[i];
        float wb = sumew[i] / fmaxf((float)deg, 1.0f);
        x1[(size_t)i * DF + lane] = c0 + b0 * wb;
        x1[(size_t)i * DF + 64 + lane] = c1 + b1 * wb;
    }
}

__device__ __forceinline__ float gelu_exact(float v) {
    return 0.5f * v * (1.0f + erff(v * 0.70710678118654752440f));
}

__global__ __launch_bounds__(256) void gemm2_k(
    const float* __restrict__ agg, const float* __restrict__ W,
    const float* __restrict__ bl, const float* __restrict__ sumew,
    const int* __restrict__ rowptr, const float* __restrict__ x1,
    const float* __restrict__ gamma, const float* __restrict__ beta,
    float* __restrict__ out, int N) {
    __shared__ float Ws[DF][DF];
    {
        const float4* Wv = (const float4*)W;
        float4* Sv = (float4*)&Ws[0][0];
        for (int idx = threadIdx.x; idx < DF * DF / 4; idx += blockDim.x) Sv[idx] = Wv[idx];
    }
    __syncthreads();
    int w = threadIdx.x >> 6, lane = threadIdx.x & 63;
    float b0 = bl[lane], b1 = bl[64 + lane];
    float g0 = gamma[lane], g1 = gamma[64 + lane];
    float be0 = beta[lane], be1 = beta[64 + lane];
    for (int i = blockIdx.x * 4 + w; i < N; i += gridDim.x * 4) {
        float r0 = agg[(size_t)i * DF + lane];
        float r1 = agg[(size_t)i * DF + 64 + lane];
        float c0 = 0.f, c1 = 0.f;
#pragma unroll 16
        for (int k = 0; k < 64; ++k) {
            float a = __shfl(r0, k);
            c0 += a * Ws[k][lane];
            c1 += a * Ws[k][64 + lane];
        }
#pragma unroll 16
        for (int k = 0; k < 64; ++k) {
            float a = __shfl(r1, k);
            c0 += a * Ws[64 + k][lane];
            c1 += a * Ws[64 + k][64 + lane];
        }
        int deg = rowptr[i + 1] - rowptr[i];
        float wb = (sumew[i] + 1.0f) / (float)(deg + 1);
        float pre0 = c0 + b0 * wb + x1[(size_t)i * DF + lane];
        float pre1 = c1 + b1 * wb + x1[(size_t)i * DF + 64 + lane];
        // LayerNorm over 128 via wave reduction
        float s = pre0 + pre1;
#pragma unroll
        for (int off = 1; off < 64; off <<= 1) s += __shfl_xor(s, off);
        float mu = s * (1.0f / 128.0f);
        float d0 = pre0 - mu, d1 = pre1 - mu;
        float vs = d0 * d0 + d1 * d1;
#pragma unroll
        for (int off = 1; off < 64; off <<= 1) vs += __shfl_xor(vs, off);
        float rstd = rsqrtf(vs * (1.0f / 128.0f) + 1e-5f);
        float y0 = d0 * rstd * g0 + be0;
        float y1 = d1 * rstd * g1 + be1;
        out[(size_t)i * DF + lane] = gelu_exact(y0);
        out[(size_t)i * DF + 64 + lane] = gelu_exact(y1);
    }
}

// ---------------- launch ----------------

extern "C" void kernel_launch(void* const* d_in, const int* in_sizes, int n_in,
                              void* d_out, int out_size, void* d_ws, size_t ws_size,
                              hipStream_t stream) {
    const float* x     = (const float*)d_in[0];
    const int*   ei    = (const int*)d_in[1];
    const float* ew    = (const float*)d_in[2];
    const float* Wl1   = (const float*)d_in[3];
    const float* bl1   = (const float*)d_in[4];
    const float* Wl2   = (const float*)d_in[5];
    const float* bl2   = (const float*)d_in[6];
    const float* gamma = (const float*)d_in[7];
    const float* beta  = (const float*)d_in[8];
    float* out = (float*)d_out;

    int N = in_sizes[0] / DF;
    int E = in_sizes[2];
    const int* src = ei;
    const int* dst = ei + E;

    char* ws = (char*)d_ws;
    size_t off = 0;
    auto alloc = [&](size_t bytes) -> void* {
        void* p = ws + off;
        off += (bytes + 255) & ~(size_t)255;
        return p;
    };
    int*   cnt     = (int*)alloc((size_t)N * 4);
    float* sumew   = (float*)alloc((size_t)N * 4);
    int*   rowptr  = (int*)alloc((size_t)(N + 1) * 4);
    int*   cursor  = (int*)alloc((size_t)N * 4);
    int*   adj_src = (int*)alloc((size_t)E * 4);
    float* adj_w   = (float*)alloc((size_t)E * 4);
    float* agg     = (float*)alloc((size_t)N * DF * 4);
    float* x1      = (float*)alloc((size_t)N * DF * 4);

    hipMemsetAsync(cnt, 0, (size_t)N * 4, stream);
    hipMemsetAsync(sumew, 0, (size_t)N * 4, stream);

    int eb = (E + 255) / 256;
    hipLaunchKernelGGL(hist_k, dim3(eb), dim3(256), 0, stream, dst, ew, cnt, sumew, E);
    hipLaunchKernelGGL(scan_k, dim3(1), dim3(256), 0, stream, cnt, rowptr, cursor, N);
    hipLaunchKernelGGL(fill_k, dim3(eb), dim3(256), 0, stream, src, dst, ew, cursor, adj_src, adj_w, E);

    int nb = (N + 3) / 4;  // 4 waves (nodes) per 256-thread block
    hipLaunchKernelGGL(agg_k<0>, dim3(nb), dim3(256), 0, stream, x, rowptr, adj_src, adj_w, agg, N);
    hipLaunchKernelGGL(gemm1_k, dim3(512), dim3(256), 0, stream, agg, Wl1, bl1, sumew, rowptr, x1, N);
    hipLaunchKernelGGL(agg_k<1>, dim3(nb), dim3(256), 0, stream, x1, rowptr, adj_src, adj_w, agg, N);
    hipLaunchKernelGGL(gemm2_k, dim3(512), dim3(256), 0, stream, agg, Wl2, bl2, sumew, rowptr, x1,
                       gamma, beta, out, N);
}

// Round 2
// 397.106 us; speedup vs baseline: 1.7274x; 1.7274x over previous
//
#include <hip/hip_runtime.h>
#include <math.h>

#define DF 128

typedef __attribute__((ext_vector_type(8))) short bf16x8;
typedef __attribute__((ext_vector_type(4))) float f32x4;

__device__ __forceinline__ float bf2f(uint u) {
    union { uint i; float f; } v; v.i = u << 16; return v.f;
}
__device__ __forceinline__ uint f2bf(float f) {  // round-to-nearest-even
    union { float f; uint i; } v; v.f = f;
    return (v.i + 0x7fffu + ((v.i >> 16) & 1u)) >> 16;
}

// ---------------- CSR build ----------------

__global__ void hist_k(const int* __restrict__ dst, const float* __restrict__ ew,
                       int* __restrict__ cnt, float* __restrict__ sumew, int E) {
    int i = blockIdx.x * blockDim.x + threadIdx.x;
    if (i < E) {
        int d = dst[i];
        atomicAdd(&cnt[d], 1);
        atomicAdd(&sumew[d], ew[i]);
    }
}

__global__ void scan_k(const int* __restrict__ cnt, int* __restrict__ rowptr,
                       int* __restrict__ cursor, int N) {
    const int T = 256;
    int t = threadIdx.x;
    int chunk = (N + T - 1) / T;
    int lo = t * chunk;
    int hi = min(lo + chunk, N);
    int s = 0;
    for (int i = lo; i < hi; ++i) s += cnt[i];
    __shared__ int sm[T];
    sm[t] = s;
    __syncthreads();
    for (int off = 1; off < T; off <<= 1) {
        int v = (t >= off) ? sm[t - off] : 0;
        __syncthreads();
        sm[t] += v;
        __syncthreads();
    }
    int run = sm[t] - s;
    for (int i = lo; i < hi; ++i) {
        rowptr[i] = run;
        cursor[i] = run;
        run += cnt[i];
    }
    if (t == T - 1) rowptr[N] = sm[T - 1];
}

__global__ void fill_k(const int* __restrict__ src, const int* __restrict__ dst,
                       const float* __restrict__ ew, int* __restrict__ cursor,
                       int* __restrict__ adj_src, float* __restrict__ adj_w, int E) {
    int i = blockIdx.x * blockDim.x + threadIdx.x;
    if (i < E) {
        int p = atomicAdd(&cursor[dst[i]], 1);
        adj_src[p] = src[i];
        adj_w[p] = ew[i];
    }
}

// ---------------- dtype prep ----------------

// x fp32 -> bf16 packed pairs
__global__ void cvt_x_k(const float* __restrict__ x, uint* __restrict__ xb, int n2) {
    int i = blockIdx.x * blockDim.x + threadIdx.x;
    if (i < n2) {
        float2 v = ((const float2*)x)[i];
        xb[i] = f2bf(v.x) | (f2bf(v.y) << 16);
    }
}

// W[k][n] fp32 -> Wt[n][k] bf16 (packed pairs along k), both weights in one launch
__global__ void cvtW_k(const float* __restrict__ W1, const float* __restrict__ W2,
                       uint* __restrict__ Wt1, uint* __restrict__ Wt2) {
    int i = blockIdx.x * blockDim.x + threadIdx.x;  // 0..16383
    const float* W = (i < 8192) ? W1 : W2;
    uint* Wt = (i < 8192) ? Wt1 : Wt2;
    int j = i & 8191;
    int n = j >> 6, kk = j & 63;
    Wt[n * 64 + kk] = f2bf(W[(2 * kk) * DF + n]) | (f2bf(W[(2 * kk + 1) * DF + n]) << 16);
}

// ---------------- aggregation (pull, one wave per node, bf16 rows) ----------------

template <int SELF>
__global__ void agg_k(const uint* __restrict__ xb, const int* __restrict__ rowptr,
                      const int* __restrict__ adj_src, const float* __restrict__ adj_w,
                      uint* __restrict__ aggb, int N) {
    int wid = (blockIdx.x * blockDim.x + threadIdx.x) >> 6;
    int lane = threadIdx.x & 63;
    if (wid >= N) return;
    int lo = rowptr[wid], hi = rowptr[wid + 1];
    float a0 = 0.f, a1 = 0.f;
    if (SELF) {
        uint v = xb[(size_t)wid * 64 + lane];
        a0 = bf2f(v & 0xffffu);
        a1 = bf2f(v >> 16);
    }
#pragma unroll 4
    for (int p = lo; p < hi; ++p) {
        int s = adj_src[p];
        float w = adj_w[p];
        uint v = xb[(size_t)s * 64 + lane];
        a0 += w * bf2f(v & 0xffffu);
        a1 += w * bf2f(v >> 16);
    }
    float inv = SELF ? 1.0f / (float)(hi - lo + 1)
                     : 1.0f / fmaxf((float)(hi - lo), 1.0f);
    aggb[(size_t)wid * 64 + lane] = f2bf(a0 * inv) | (f2bf(a1 * inv) << 16);
}

// ---------------- MFMA GEMMs: one wave per 16-row strip ----------------
// A frag: row=lane&15, k=(lane>>4)*8+j  (contiguous 8 bf16 in agg row)
// B frag: col=lane&15, k=(lane>>4)*8+j  (contiguous 8 bf16 in Wt row)
// D:      col=lane&15, row=(lane>>4)*4+reg   [m89-verified]

__global__ __launch_bounds__(256) void mm1_k(
    const ushort* __restrict__ aggb, const ushort* __restrict__ Wt,
    const float* __restrict__ bl, const float* __restrict__ sumew,
    const int* __restrict__ rowptr, float* __restrict__ x1,
    ushort* __restrict__ x1b, int N) {
    int lane = threadIdx.x & 63;
    int strip = blockIdx.x * 4 + (threadIdx.x >> 6);
    int nstrips = (N + 15) >> 4;
    if (strip >= nstrips) return;
    int row0 = strip << 4;
    int arow = row0 + (lane & 15);
    if (arow >= N) arow = N - 1;
    int kg = (lane >> 4) << 3;
    int bcol = lane & 15;

    bf16x8 af[4];
#pragma unroll
    for (int kc = 0; kc < 4; ++kc)
        af[kc] = *(const bf16x8*)(aggb + (size_t)arow * DF + kc * 32 + kg);

    f32x4 acc[8];
#pragma unroll
    for (int nt = 0; nt < 8; ++nt) {
        f32x4 a = {0.f, 0.f, 0.f, 0.f};
#pragma unroll
        for (int kc = 0; kc < 4; ++kc) {
            bf16x8 bf = *(const bf16x8*)(Wt + (size_t)(nt * 16 + bcol) * DF + kc * 32 + kg);
            a = __builtin_amdgcn_mfma_f32_16x16x32_bf16(af[kc], bf, a, 0, 0, 0);
        }
        acc[nt] = a;
    }

#pragma unroll
    for (int r = 0; r < 4; ++r) {
        int R = row0 + ((lane >> 4) << 2) + r;
        if (R >= N) continue;
        int deg = rowptr[R + 1] - rowptr[R];
        float wb = sumew[R] / fmaxf((float)deg, 1.0f);
#pragma unroll
        for (int nt = 0; nt < 8; ++nt) {
            int col = nt * 16 + bcol;
            float v = acc[nt][r] + bl[col] * wb;
            x1[(size_t)R * DF + col] = v;
            x1b[(size_t)R * DF + col] = (ushort)f2bf(v);
        }
    }
}

__device__ __forceinline__ float gelu_exact(float v) {
    return 0.5f * v * (1.0f + erff(v * 0.70710678118654752440f));
}

__global__ __launch_bounds__(256) void mm2_k(
    const ushort* __restrict__ aggb, const ushort* __restrict__ Wt,
    const float* __restrict__ bl, const float* __restrict__ sumew,
    const int* __restrict__ rowptr, const float* __restrict__ x1,
    const float* __restrict__ gamma, const float* __restrict__ beta,
    float* __restrict__ out, int N) {
    int lane = threadIdx.x & 63;
    int strip = blockIdx.x * 4 + (threadIdx.x >> 6);
    int nstrips = (N + 15) >> 4;
    if (strip >= nstrips) return;
    int row0 = strip << 4;
    int arow = row0 + (lane & 15);
    if (arow >= N) arow = N - 1;
    int kg = (lane >> 4) << 3;
    int bcol = lane & 15;

    bf16x8 af[4];
#pragma unroll
    for (int kc = 0; kc < 4; ++kc)
        af[kc] = *(const bf16x8*)(aggb + (size_t)arow * DF + kc * 32 + kg);

    f32x4 acc[8];
#pragma unroll
    for (int nt = 0; nt < 8; ++nt) {
        f32x4 a = {0.f, 0.f, 0.f, 0.f};
#pragma unroll
        for (int kc = 0; kc < 4; ++kc) {
            bf16x8 bf = *(const bf16x8*)(Wt + (size_t)(nt * 16 + bcol) * DF + kc * 32 + kg);
            a = __builtin_amdgcn_mfma_f32_16x16x32_bf16(af[kc], bf, a, 0, 0, 0);
        }
        acc[nt] = a;
    }

#pragma unroll
    for (int r = 0; r < 4; ++r) {
        int R = row0 + ((lane >> 4) << 2) + r;
        if (R >= N) continue;
        int deg = rowptr[R + 1] - rowptr[R];
        float wb = (sumew[R] + 1.0f) / (float)(deg + 1);
        float pre[8];
        float s = 0.f;
#pragma unroll
        for (int nt = 0; nt < 8; ++nt) {
            int col = nt * 16 + bcol;
            pre[nt] = acc[nt][r] + bl[col] * wb + x1[(size_t)R * DF + col];
            s += pre[nt];
        }
        // row-wide LN reduction across the 16 lanes sharing this row
        s += __shfl_xor(s, 1);
        s += __shfl_xor(s, 2);
        s += __shfl_xor(s, 4);
        s += __shfl_xor(s, 8);
        float mu = s * (1.0f / 128.0f);
        float vs = 0.f;
#pragma unroll
        for (int nt = 0; nt < 8; ++nt) {
            float d = pre[nt] - mu;
            vs += d * d;
        }
        vs += __shfl_xor(vs, 1);
        vs += __shfl_xor(vs, 2);
        vs += __shfl_xor(vs, 4);
        vs += __shfl_xor(vs, 8);
        float rstd = rsqrtf(vs * (1.0f / 128.0f) + 1e-5f);
#pragma unroll
        for (int nt = 0; nt < 8; ++nt) {
            int col = nt * 16 + bcol;
            float y = (pre[nt] - mu) * rstd * gamma[col] + beta[col];
            out[(size_t)R * DF + col] = gelu_exact(y);
        }
    }
}

// ---------------- launch ----------------

extern "C" void kernel_launch(void* const* d_in, const int* in_sizes, int n_in,
                              void* d_out, int out_size, void* d_ws, size_t ws_size,
                              hipStream_t stream) {
    const float* x     = (const float*)d_in[0];
    const int*   ei    = (const int*)d_in[1];
    const float* ew    = (const float*)d_in[2];
    const float* Wl1   = (const float*)d_in[3];
    const float* bl1   = (const float*)d_in[4];
    const float* Wl2   = (const float*)d_in[5];
    const float* bl2   = (const float*)d_in[6];
    const float* gamma = (const float*)d_in[7];
    const float* beta  = (const float*)d_in[8];
    float* out = (float*)d_out;

    int N = in_sizes[0] / DF;
    int E = in_sizes[2];
    const int* src = ei;
    const int* dst = ei + E;

    char* ws = (char*)d_ws;
    size_t off = 0;
    auto alloc = [&](size_t bytes) -> void* {
        void* p = ws + off;
        off += (bytes + 255) & ~(size_t)255;
        return p;
    };
    int*    cnt     = (int*)alloc((size_t)N * 4);
    float*  sumew   = (float*)alloc((size_t)N * 4);
    int*    rowptr  = (int*)alloc((size_t)(N + 1) * 4);
    int*    cursor  = (int*)alloc((size_t)N * 4);
    int*    adj_src = (int*)alloc((size_t)E * 4);
    float*  adj_w   = (float*)alloc((size_t)E * 4);
    uint*   xb      = (uint*)alloc((size_t)N * DF * 2);   // bf16 x
    uint*   aggb    = (uint*)alloc((size_t)N * DF * 2);   // bf16 aggregation
    float*  x1      = (float*)alloc((size_t)N * DF * 4);  // fp32 x1 (residual)
    ushort* x1b     = (ushort*)alloc((size_t)N * DF * 2); // bf16 x1 (gather)
    uint*   Wt1     = (uint*)alloc((size_t)DF * DF * 2);
    uint*   Wt2     = (uint*)alloc((size_t)DF * DF * 2);

    hipMemsetAsync(cnt, 0, (size_t)N * 4, stream);
    hipMemsetAsync(sumew, 0, (size_t)N * 4, stream);

    int eb = (E + 255) / 256;
    hipLaunchKernelGGL(hist_k, dim3(eb), dim3(256), 0, stream, dst, ew, cnt, sumew, E);
    hipLaunchKernelGGL(scan_k, dim3(1), dim3(256), 0, stream, cnt, rowptr, cursor, N);
    hipLaunchKernelGGL(fill_k, dim3(eb), dim3(256), 0, stream, src, dst, ew, cursor, adj_src, adj_w, E);

    int n2 = N * DF / 2;
    hipLaunchKernelGGL(cvt_x_k, dim3((n2 + 255) / 256), dim3(256), 0, stream, x, xb, n2);
    hipLaunchKernelGGL(cvtW_k, dim3(64), dim3(256), 0, stream, Wl1, Wl2, Wt1, Wt2);

    int nb = (N * 64 + 255) / 256;  // one wave per node
    int nstrips = (N + 15) / 16;
    int mb = (nstrips + 3) / 4;     // one wave per 16-row strip

    hipLaunchKernelGGL(agg_k<0>, dim3(nb), dim3(256), 0, stream, xb, rowptr, adj_src, adj_w, aggb, N);
    hipLaunchKernelGGL(mm1_k, dim3(mb), dim3(256), 0, stream,
                       (const ushort*)aggb, (const ushort*)Wt1, bl1, sumew, rowptr, x1, x1b, N);
    hipLaunchKernelGGL(agg_k<1>, dim3(nb), dim3(256), 0, stream, (const uint*)x1b, rowptr, adj_src, adj_w, aggb, N);
    hipLaunchKernelGGL(mm2_k, dim3(mb), dim3(256), 0, stream,
                       (const ushort*)aggb, (const ushort*)Wt2, bl2, sumew, rowptr, x1, gamma, beta, out, N);
}

// Round 3
// 277.090 us; speedup vs baseline: 2.4756x; 1.4331x over previous
//
#include <hip/hip_runtime.h>
#include <math.h>

#define DF 128

typedef __attribute__((ext_vector_type(8))) short bf16x8;
typedef __attribute__((ext_vector_type(4))) float f32x4;

__device__ __forceinline__ float bf2f(uint u) {
    union { uint i; float f; } v; v.i = u << 16; return v.f;
}
__device__ __forceinline__ uint f2bf(float f) {  // round-to-nearest-even
    union { float f; uint i; } v; v.f = f;
    return (v.i + 0x7fffu + ((v.i >> 16) & 1u)) >> 16;
}

// ---------------- fused prep: cvt_x + cvtW + hist ----------------

__global__ void prep_k(const float* __restrict__ x, uint* __restrict__ xb, int n2,
                       const float* __restrict__ W1, const float* __restrict__ W2,
                       uint* __restrict__ Wt1, uint* __restrict__ Wt2,
                       const int* __restrict__ dst, const float* __restrict__ ew,
                       int* __restrict__ cnt, float* __restrict__ sumew, int E,
                       int cvtxB) {
    int b = blockIdx.x;
    if (b < cvtxB) {
        int i = b * 256 + threadIdx.x;
        if (i < n2) {
            float2 v = ((const float2*)x)[i];
            xb[i] = f2bf(v.x) | (f2bf(v.y) << 16);
        }
    } else if (b < cvtxB + 64) {
        int i = (b - cvtxB) * 256 + threadIdx.x;  // 0..16383
        const float* W = (i < 8192) ? W1 : W2;
        uint* Wt = (i < 8192) ? Wt1 : Wt2;
        int j = i & 8191;
        int n = j >> 6, kk = j & 63;
        Wt[n * 64 + kk] = f2bf(W[(2 * kk) * DF + n]) | (f2bf(W[(2 * kk + 1) * DF + n]) << 16);
    } else {
        int i = (b - cvtxB - 64) * 256 + threadIdx.x;
        if (i < E) {
            int d = dst[i];
            atomicAdd(&cnt[d], 1);
            atomicAdd(&sumew[d], ew[i]);
        }
    }
}

// ---------------- parallel scan (3 stages) ----------------

__global__ void partial_k(const int* __restrict__ cnt, int* __restrict__ bsum, int N) {
    int t = threadIdx.x, b = blockIdx.x;
    int base = b * 1024 + t * 4;
    int s = 0;
    if (base + 4 <= N) {
        int4 v = *(const int4*)(cnt + base);
        s = v.x + v.y + v.z + v.w;
    } else {
        for (int j = 0; j < 4; ++j)
            if (base + j < N) s += cnt[base + j];
    }
    __shared__ int sm[256];
    sm[t] = s;
    __syncthreads();
    for (int off = 128; off > 0; off >>= 1) {
        if (t < off) sm[t] += sm[t + off];
        __syncthreads();
    }
    if (t == 0) bsum[b] = sm[0];
}

// single block: exclusive scan of <=256 block sums; also writes rowptr[N]
__global__ void scanb_k(const int* __restrict__ bsum, int* __restrict__ boff,
                        int* __restrict__ rowptr, int nb, int N) {
    int t = threadIdx.x;
    int v = (t < nb) ? bsum[t] : 0;
    __shared__ int sm[256];
    sm[t] = v;
    __syncthreads();
    for (int off = 1; off < 256; off <<= 1) {
        int u = (t >= off) ? sm[t - off] : 0;
        __syncthreads();
        sm[t] += u;
        __syncthreads();
    }
    if (t < nb) boff[t] = sm[t] - v;
    if (t == 255) rowptr[N] = sm[255];
}

__global__ void rowfill_k(const int* __restrict__ cnt, const int* __restrict__ boff,
                          int* __restrict__ rowptr, int* __restrict__ cursor, int N) {
    int t = threadIdx.x, b = blockIdx.x;
    int base = b * 1024 + t * 4;
    int c0 = 0, c1 = 0, c2 = 0, c3 = 0;
    if (base + 4 <= N) {
        int4 v = *(const int4*)(cnt + base);
        c0 = v.x; c1 = v.y; c2 = v.z; c3 = v.w;
    } else {
        if (base + 0 < N) c0 = cnt[base + 0];
        if (base + 1 < N) c1 = cnt[base + 1];
        if (base + 2 < N) c2 = cnt[base + 2];
        if (base + 3 < N) c3 = cnt[base + 3];
    }
    int s = c0 + c1 + c2 + c3;
    __shared__ int sm[256];
    sm[t] = s;
    __syncthreads();
    for (int off = 1; off < 256; off <<= 1) {
        int u = (t >= off) ? sm[t - off] : 0;
        __syncthreads();
        sm[t] += u;
        __syncthreads();
    }
    int run = boff[b] + sm[t] - s;
    if (base + 0 < N) { rowptr[base + 0] = run; cursor[base + 0] = run; run += c0; }
    if (base + 1 < N) { rowptr[base + 1] = run; cursor[base + 1] = run; run += c1; }
    if (base + 2 < N) { rowptr[base + 2] = run; cursor[base + 2] = run; run += c2; }
    if (base + 3 < N) { rowptr[base + 3] = run; cursor[base + 3] = run; run += c3; }
}

__global__ void fill_k(const int* __restrict__ src, const int* __restrict__ dst,
                       const float* __restrict__ ew, int* __restrict__ cursor,
                       int* __restrict__ adj_src, float* __restrict__ adj_w, int E) {
    int i = blockIdx.x * blockDim.x + threadIdx.x;
    if (i < E) {
        int p = atomicAdd(&cursor[dst[i]], 1);
        adj_src[p] = src[i];
        adj_w[p] = ew[i];
    }
}

// ---------------- aggregation (pull, one wave per node, lane-batched adjacency) ----------------

template <int SELF>
__global__ void agg_k(const uint* __restrict__ xb, const int* __restrict__ rowptr,
                      const int* __restrict__ adj_src, const float* __restrict__ adj_w,
                      uint* __restrict__ aggb, int N) {
    int wid = (blockIdx.x * blockDim.x + threadIdx.x) >> 6;
    int lane = threadIdx.x & 63;
    if (wid >= N) return;
    int lo = rowptr[wid], hi = rowptr[wid + 1];
    float a0 = 0.f, a1 = 0.f;
    if (SELF) {
        uint v = xb[(size_t)wid * 64 + lane];
        a0 = bf2f(v & 0xffffu);
        a1 = bf2f(v >> 16);
    }
    for (int base = lo; base < hi; base += 64) {
        int p = base + lane;
        int sidx = 0; float wv = 0.f;
        if (p < hi) { sidx = adj_src[p]; wv = adj_w[p]; }
        int cnt = min(hi - base, 64);
        int j = 0;
        for (; j + 4 <= cnt; j += 4) {
            int s0 = __shfl(sidx, j),     s1 = __shfl(sidx, j + 1);
            int s2 = __shfl(sidx, j + 2), s3 = __shfl(sidx, j + 3);
            float w0 = __shfl(wv, j),     w1 = __shfl(wv, j + 1);
            float w2 = __shfl(wv, j + 2), w3 = __shfl(wv, j + 3);
            uint v0 = xb[(size_t)s0 * 64 + lane];
            uint v1 = xb[(size_t)s1 * 64 + lane];
            uint v2 = xb[(size_t)s2 * 64 + lane];
            uint v3 = xb[(size_t)s3 * 64 + lane];
            a0 += w0 * bf2f(v0 & 0xffffu); a1 += w0 * bf2f(v0 >> 16);
            a0 += w1 * bf2f(v1 & 0xffffu); a1 += w1 * bf2f(v1 >> 16);
            a0 += w2 * bf2f(v2 & 0xffffu); a1 += w2 * bf2f(v2 >> 16);
            a0 += w3 * bf2f(v3 & 0xffffu); a1 += w3 * bf2f(v3 >> 16);
        }
        for (; j < cnt; ++j) {
            int sj = __shfl(sidx, j);
            float wj = __shfl(wv, j);
            uint v = xb[(size_t)sj * 64 + lane];
            a0 += wj * bf2f(v & 0xffffu);
            a1 += wj * bf2f(v >> 16);
        }
    }
    float inv = SELF ? 1.0f / (float)(hi - lo + 1)
                     : 1.0f / fmaxf((float)(hi - lo), 1.0f);
    aggb[(size_t)wid * 64 + lane] = f2bf(a0 * inv) | (f2bf(a1 * inv) << 16);
}

// ---------------- MFMA GEMMs: one wave per 16-row strip ----------------
// A frag: row=lane&15, k=(lane>>4)*8+j ; B frag: col=lane&15, same k
// D: col=lane&15, row=(lane>>4)*4+reg   [m89-verified]

__global__ __launch_bounds__(256) void mm1_k(
    const ushort* __restrict__ aggb, const ushort* __restrict__ Wt,
    const float* __restrict__ bl, const float* __restrict__ sumew,
    const int* __restrict__ rowptr, float* __restrict__ x1,
    ushort* __restrict__ x1b, int N) {
    int lane = threadIdx.x & 63;
    int strip = blockIdx.x * 4 + (threadIdx.x >> 6);
    int nstrips = (N + 15) >> 4;
    if (strip >= nstrips) return;
    int row0 = strip << 4;
    int arow = row0 + (lane & 15);
    if (arow >= N) arow = N - 1;
    int kg = (lane >> 4) << 3;
    int bcol = lane & 15;

    bf16x8 af[4];
#pragma unroll
    for (int kc = 0; kc < 4; ++kc)
        af[kc] = *(const bf16x8*)(aggb + (size_t)arow * DF + kc * 32 + kg);

    f32x4 acc[8];
#pragma unroll
    for (int nt = 0; nt < 8; ++nt) {
        f32x4 a = {0.f, 0.f, 0.f, 0.f};
#pragma unroll
        for (int kc = 0; kc < 4; ++kc) {
            bf16x8 bf = *(const bf16x8*)(Wt + (size_t)(nt * 16 + bcol) * DF + kc * 32 + kg);
            a = __builtin_amdgcn_mfma_f32_16x16x32_bf16(af[kc], bf, a, 0, 0, 0);
        }
        acc[nt] = a;
    }

#pragma unroll
    for (int r = 0; r < 4; ++r) {
        int R = row0 + ((lane >> 4) << 2) + r;
        if (R >= N) continue;
        int deg = rowptr[R + 1] - rowptr[R];
        float wb = sumew[R] / fmaxf((float)deg, 1.0f);
#pragma unroll
        for (int nt = 0; nt < 8; ++nt) {
            int col = nt * 16 + bcol;
            float v = acc[nt][r] + bl[col] * wb;
            x1[(size_t)R * DF + col] = v;
            x1b[(size_t)R * DF + col] = (ushort)f2bf(v);
        }
    }
}

__device__ __forceinline__ float gelu_exact(float v) {
    return 0.5f * v * (1.0f + erff(v * 0.70710678118654752440f));
}

__global__ __launch_bounds__(256) void mm2_k(
    const ushort* __restrict__ aggb, const ushort* __restrict__ Wt,
    const float* __restrict__ bl, const float* __restrict__ sumew,
    const int* __restrict__ rowptr, const float* __restrict__ x1,
    const float* __restrict__ gamma, const float* __restrict__ beta,
    float* __restrict__ out, int N) {
    int lane = threadIdx.x & 63;
    int strip = blockIdx.x * 4 + (threadIdx.x >> 6);
    int nstrips = (N + 15) >> 4;
    if (strip >= nstrips) return;
    int row0 = strip << 4;
    int arow = row0 + (lane & 15);
    if (arow >= N) arow = N - 1;
    int kg = (lane >> 4) << 3;
    int bcol = lane & 15;

    bf16x8 af[4];
#pragma unroll
    for (int kc = 0; kc < 4; ++kc)
        af[kc] = *(const bf16x8*)(aggb + (size_t)arow * DF + kc * 32 + kg);

    f32x4 acc[8];
#pragma unroll
    for (int nt = 0; nt < 8; ++nt) {
        f32x4 a = {0.f, 0.f, 0.f, 0.f};
#pragma unroll
        for (int kc = 0; kc < 4; ++kc) {
            bf16x8 bf = *(const bf16x8*)(Wt + (size_t)(nt * 16 + bcol) * DF + kc * 32 + kg);
            a = __builtin_amdgcn_mfma_f32_16x16x32_bf16(af[kc], bf, a, 0, 0, 0);
        }
        acc[nt] = a;
    }

#pragma unroll
    for (int r = 0; r < 4; ++r) {
        int R = row0 + ((lane >> 4) << 2) + r;
        if (R >= N) continue;
        int deg = rowptr[R + 1] - rowptr[R];
        float wb = (sumew[R] + 1.0f) / (float)(deg + 1);
        float pre[8];
        float s = 0.f;
#pragma unroll
        for (int nt = 0; nt < 8; ++nt) {
            int col = nt * 16 + bcol;
            pre[nt] = acc[nt][r] + bl[col] * wb + x1[(size_t)R * DF + col];
            s += pre[nt];
        }
        s += __shfl_xor(s, 1);
        s += __shfl_xor(s, 2);
        s += __shfl_xor(s, 4);
        s += __shfl_xor(s, 8);
        float mu = s * (1.0f / 128.0f);
        float vs = 0.f;
#pragma unroll
        for (int nt = 0; nt < 8; ++nt) {
            float d = pre[nt] - mu;
            vs += d * d;
        }
        vs += __shfl_xor(vs, 1);
        vs += __shfl_xor(vs, 2);
        vs += __shfl_xor(vs, 4);
        vs += __shfl_xor(vs, 8);
        float rstd = rsqrtf(vs * (1.0f / 128.0f) + 1e-5f);
#pragma unroll
        for (int nt = 0; nt < 8; ++nt) {
            int col = nt * 16 + bcol;
            float y = (pre[nt] - mu) * rstd * gamma[col] + beta[col];
            out[(size_t)R * DF + col] = gelu_exact(y);
        }
    }
}

// ---------------- launch ----------------

extern "C" void kernel_launch(void* const* d_in, const int* in_sizes, int n_in,
                              void* d_out, int out_size, void* d_ws, size_t ws_size,
                              hipStream_t stream) {
    const float* x     = (const float*)d_in[0];
    const int*   ei    = (const int*)d_in[1];
    const float* ew    = (const float*)d_in[2];
    const float* Wl1   = (const float*)d_in[3];
    const float* bl1   = (const float*)d_in[4];
    const float* Wl2   = (const float*)d_in[5];
    const float* bl2   = (const float*)d_in[6];
    const float* gamma = (const float*)d_in[7];
    const float* beta  = (const float*)d_in[8];
    float* out = (float*)d_out;

    int N = in_sizes[0] / DF;
    int E = in_sizes[2];
    const int* src = ei;
    const int* dst = ei + E;

    char* ws = (char*)d_ws;
    size_t off = 0;
    auto alloc = [&](size_t bytes) -> void* {
        void* p = ws + off;
        off += (bytes + 255) & ~(size_t)255;
        return p;
    };
    int*    cnt     = (int*)alloc((size_t)N * 4);
    float*  sumew   = (float*)alloc((size_t)N * 4);
    int*    rowptr  = (int*)alloc((size_t)(N + 1) * 4);
    int*    cursor  = (int*)alloc((size_t)N * 4);
    int*    bsum    = (int*)alloc(1024);
    int*    boff    = (int*)alloc(1024);
    int*    adj_src = (int*)alloc((size_t)E * 4);
    float*  adj_w   = (float*)alloc((size_t)E * 4);
    uint*   xb      = (uint*)alloc((size_t)N * DF * 2);
    uint*   aggb    = (uint*)alloc((size_t)N * DF * 2);
    float*  x1      = (float*)alloc((size_t)N * DF * 4);
    ushort* x1b     = (ushort*)alloc((size_t)N * DF * 2);
    uint*   Wt1     = (uint*)alloc((size_t)DF * DF * 2);
    uint*   Wt2     = (uint*)alloc((size_t)DF * DF * 2);

    hipMemsetAsync(cnt, 0, (size_t)N * 4, stream);
    hipMemsetAsync(sumew, 0, (size_t)N * 4, stream);

    int n2 = N * DF / 2;
    int cvtxB = (n2 + 255) / 256;
    int eb = (E + 255) / 256;
    hipLaunchKernelGGL(prep_k, dim3(cvtxB + 64 + eb), dim3(256), 0, stream,
                       x, xb, n2, Wl1, Wl2, Wt1, Wt2, dst, ew, cnt, sumew, E, cvtxB);

    int nb_scan = (N + 1023) / 1024;
    hipLaunchKernelGGL(partial_k, dim3(nb_scan), dim3(256), 0, stream, cnt, bsum, N);
    hipLaunchKernelGGL(scanb_k, dim3(1), dim3(256), 0, stream, bsum, boff, rowptr, nb_scan, N);
    hipLaunchKernelGGL(rowfill_k, dim3(nb_scan), dim3(256), 0, stream, cnt, boff, rowptr, cursor, N);
    hipLaunchKernelGGL(fill_k, dim3(eb), dim3(256), 0, stream, src, dst, ew, cursor, adj_src, adj_w, E);

    int nb = (N * 64 + 255) / 256;
    int nstrips = (N + 15) / 16;
    int mb = (nstrips + 3) / 4;

    hipLaunchKernelGGL(agg_k<0>, dim3(nb), dim3(256), 0, stream, xb, rowptr, adj_src, adj_w, aggb, N);
    hipLaunchKernelGGL(mm1_k, dim3(mb), dim3(256), 0, stream,
                       (const ushort*)aggb, (const ushort*)Wt1, bl1, sumew, rowptr, x1, x1b, N);
    hipLaunchKernelGGL(agg_k<1>, dim3(nb), dim3(256), 0, stream, (const uint*)x1b, rowptr, adj_src, adj_w, aggb, N);
    hipLaunchKernelGGL(mm2_k, dim3(mb), dim3(256), 0, stream,
                       (const ushort*)aggb, (const ushort*)Wt2, bl2, sumew, rowptr, x1, gamma, beta, out, N);
}

// Round 4
// 228.245 us; speedup vs baseline: 3.0054x; 1.2140x over previous
//
#include <hip/hip_runtime.h>
#include <math.h>

#define DF 128

typedef __attribute__((ext_vector_type(8))) short bf16x8;
typedef __attribute__((ext_vector_type(4))) float f32x4;

__device__ __forceinline__ float bf2f(uint u) {
    union { uint i; float f; } v; v.i = u << 16; return v.f;
}
__device__ __forceinline__ uint f2bf(float f) {  // round-to-nearest-even
    union { float f; uint i; } v; v.f = f;
    return (v.i + 0x7fffu + ((v.i >> 16) & 1u)) >> 16;
}

// ---------------- fused prep: cvt_x (float4) + cvtW + hist (cnt only, int4) ----------------

__global__ void prep_k(const float* __restrict__ x, uint* __restrict__ xb, int n4,
                       const float* __restrict__ W1, const float* __restrict__ W2,
                       uint* __restrict__ Wt1, uint* __restrict__ Wt2,
                       const int* __restrict__ dst, int* __restrict__ cnt, int E,
                       int cvtxB) {
    int b = blockIdx.x;
    if (b < cvtxB) {
        int i = b * 256 + threadIdx.x;
        if (i < n4) {
            float4 v = ((const float4*)x)[i];
            uint2 o;
            o.x = f2bf(v.x) | (f2bf(v.y) << 16);
            o.y = f2bf(v.z) | (f2bf(v.w) << 16);
            ((uint2*)xb)[i] = o;
        }
    } else if (b < cvtxB + 64) {
        int i = (b - cvtxB) * 256 + threadIdx.x;  // 0..16383
        const float* W = (i < 8192) ? W1 : W2;
        uint* Wt = (i < 8192) ? Wt1 : Wt2;
        int j = i & 8191;
        int n = j >> 6, kk = j & 63;
        Wt[n * 64 + kk] = f2bf(W[(2 * kk) * DF + n]) | (f2bf(W[(2 * kk + 1) * DF + n]) << 16);
    } else {
        int e0 = ((b - cvtxB - 64) * 256 + threadIdx.x) * 4;
        if (e0 + 4 <= E) {
            int4 d = *(const int4*)(dst + e0);
            atomicAdd(&cnt[d.x], 1);
            atomicAdd(&cnt[d.y], 1);
            atomicAdd(&cnt[d.z], 1);
            atomicAdd(&cnt[d.w], 1);
        } else {
            for (int j = e0; j < E; ++j) atomicAdd(&cnt[dst[j]], 1);
        }
    }
}

// ---------------- parallel scan (3 stages) ----------------

__global__ void partial_k(const int* __restrict__ cnt, int* __restrict__ bsum, int N) {
    int t = threadIdx.x, b = blockIdx.x;
    int base = b * 1024 + t * 4;
    int s = 0;
    if (base + 4 <= N) {
        int4 v = *(const int4*)(cnt + base);
        s = v.x + v.y + v.z + v.w;
    } else {
        for (int j = 0; j < 4; ++j)
            if (base + j < N) s += cnt[base + j];
    }
    __shared__ int sm[256];
    sm[t] = s;
    __syncthreads();
    for (int off = 128; off > 0; off >>= 1) {
        if (t < off) sm[t] += sm[t + off];
        __syncthreads();
    }
    if (t == 0) bsum[b] = sm[0];
}

__global__ void scanb_k(const int* __restrict__ bsum, int* __restrict__ boff,
                        int* __restrict__ rowptr, int nb, int N) {
    int t = threadIdx.x;
    int v = (t < nb) ? bsum[t] : 0;
    __shared__ int sm[256];
    sm[t] = v;
    __syncthreads();
    for (int off = 1; off < 256; off <<= 1) {
        int u = (t >= off) ? sm[t - off] : 0;
        __syncthreads();
        sm[t] += u;
        __syncthreads();
    }
    if (t < nb) boff[t] = sm[t] - v;
    if (t == 255) rowptr[N] = sm[255];
}

__global__ void rowfill_k(const int* __restrict__ cnt, const int* __restrict__ boff,
                          int* __restrict__ rowptr, int* __restrict__ cursor, int N) {
    int t = threadIdx.x, b = blockIdx.x;
    int base = b * 1024 + t * 4;
    int c0 = 0, c1 = 0, c2 = 0, c3 = 0;
    if (base + 4 <= N) {
        int4 v = *(const int4*)(cnt + base);
        c0 = v.x; c1 = v.y; c2 = v.z; c3 = v.w;
    } else {
        if (base + 0 < N) c0 = cnt[base + 0];
        if (base + 1 < N) c1 = cnt[base + 1];
        if (base + 2 < N) c2 = cnt[base + 2];
        if (base + 3 < N) c3 = cnt[base + 3];
    }
    int s = c0 + c1 + c2 + c3;
    __shared__ int sm[256];
    sm[t] = s;
    __syncthreads();
    for (int off = 1; off < 256; off <<= 1) {
        int u = (t >= off) ? sm[t - off] : 0;
        __syncthreads();
        sm[t] += u;
        __syncthreads();
    }
    int run = boff[b] + sm[t] - s;
    if (base + 0 < N) { rowptr[base + 0] = run; cursor[base + 0] = run; run += c0; }
    if (base + 1 < N) { rowptr[base + 1] = run; cursor[base + 1] = run; run += c1; }
    if (base + 2 < N) { rowptr[base + 2] = run; cursor[base + 2] = run; run += c2; }
    if (base + 3 < N) { rowptr[base + 3] = run; cursor[base + 3] = run; run += c3; }
}

__global__ void fill_k(const int* __restrict__ src, const int* __restrict__ dst,
                       const float* __restrict__ ew, int* __restrict__ cursor,
                       int2* __restrict__ adj, int E) {
    int i = blockIdx.x * blockDim.x + threadIdx.x;
    if (i < E) {
        int p = atomicAdd(&cursor[dst[i]], 1);
        int2 e;
        e.x = src[i];
        e.y = __float_as_int(ew[i]);
        adj[p] = e;
    }
}

// ---------------- aggregation (pull, one wave per node, packed adj, 8-wide MLP) ----------------

template <int SELF>
__global__ void agg_k(const uint* __restrict__ xb, const int* __restrict__ rowptr,
                      const int2* __restrict__ adj, uint* __restrict__ aggb,
                      float* __restrict__ sumew, int N) {
    int wid = (blockIdx.x * blockDim.x + threadIdx.x) >> 6;
    int lane = threadIdx.x & 63;
    if (wid >= N) return;
    int lo = rowptr[wid], hi = rowptr[wid + 1];
    float a0 = 0.f, a1 = 0.f, ws = 0.f;
    if (SELF) {
        uint v = xb[(size_t)wid * 64 + lane];
        a0 = bf2f(v & 0xffffu);
        a1 = bf2f(v >> 16);
    }
    for (int base = lo; base < hi; base += 64) {
        int p = base + lane;
        int sidx = 0; float wv = 0.f;
        if (p < hi) {
            int2 e = adj[p];
            sidx = e.x;
            wv = __int_as_float(e.y);
        }
        ws += wv;
        int cnt = min(hi - base, 64);
        int j = 0;
        for (; j + 8 <= cnt; j += 8) {
            int s0 = __shfl(sidx, j),     s1 = __shfl(sidx, j + 1);
            int s2 = __shfl(sidx, j + 2), s3 = __shfl(sidx, j + 3);
            int s4 = __shfl(sidx, j + 4), s5 = __shfl(sidx, j + 5);
            int s6 = __shfl(sidx, j + 6), s7 = __shfl(sidx, j + 7);
            float w0 = __shfl(wv, j),     w1 = __shfl(wv, j + 1);
            float w2 = __shfl(wv, j + 2), w3 = __shfl(wv, j + 3);
            float w4 = __shfl(wv, j + 4), w5 = __shfl(wv, j + 5);
            float w6 = __shfl(wv, j + 6), w7 = __shfl(wv, j + 7);
            uint v0 = xb[(size_t)s0 * 64 + lane];
            uint v1 = xb[(size_t)s1 * 64 + lane];
            uint v2 = xb[(size_t)s2 * 64 + lane];
            uint v3 = xb[(size_t)s3 * 64 + lane];
            uint v4 = xb[(size_t)s4 * 64 + lane];
            uint v5 = xb[(size_t)s5 * 64 + lane];
            uint v6 = xb[(size_t)s6 * 64 + lane];
            uint v7 = xb[(size_t)s7 * 64 + lane];
            a0 += w0 * bf2f(v0 & 0xffffu); a1 += w0 * bf2f(v0 >> 16);
            a0 += w1 * bf2f(v1 & 0xffffu); a1 += w1 * bf2f(v1 >> 16);
            a0 += w2 * bf2f(v2 & 0xffffu); a1 += w2 * bf2f(v2 >> 16);
            a0 += w3 * bf2f(v3 & 0xffffu); a1 += w3 * bf2f(v3 >> 16);
            a0 += w4 * bf2f(v4 & 0xffffu); a1 += w4 * bf2f(v4 >> 16);
            a0 += w5 * bf2f(v5 & 0xffffu); a1 += w5 * bf2f(v5 >> 16);
            a0 += w6 * bf2f(v6 & 0xffffu); a1 += w6 * bf2f(v6 >> 16);
            a0 += w7 * bf2f(v7 & 0xffffu); a1 += w7 * bf2f(v7 >> 16);
        }
        for (; j < cnt; ++j) {
            int sj = __shfl(sidx, j);
            float wj = __shfl(wv, j);
            uint v = xb[(size_t)sj * 64 + lane];
            a0 += wj * bf2f(v & 0xffffu);
            a1 += wj * bf2f(v >> 16);
        }
    }
    if (!SELF) {
        // wave-reduce edge-weight sum; lane 0 stores per-node sumew
        ws += __shfl_xor(ws, 1);
        ws += __shfl_xor(ws, 2);
        ws += __shfl_xor(ws, 4);
        ws += __shfl_xor(ws, 8);
        ws += __shfl_xor(ws, 16);
        ws += __shfl_xor(ws, 32);
        if (lane == 0) sumew[wid] = ws;
    }
    float inv = SELF ? 1.0f / (float)(hi - lo + 1)
                     : 1.0f / fmaxf((float)(hi - lo), 1.0f);
    aggb[(size_t)wid * 64 + lane] = f2bf(a0 * inv) | (f2bf(a1 * inv) << 16);
}

// ---------------- MFMA GEMMs: one wave per 16-row strip ----------------
// A frag: row=lane&15, k=(lane>>4)*8+j ; B frag: col=lane&15, same k
// D: col=lane&15, row=(lane>>4)*4+reg   [m89-verified]

__global__ __launch_bounds__(256) void mm1_k(
    const ushort* __restrict__ aggb, const ushort* __restrict__ Wt,
    const float* __restrict__ bl, const float* __restrict__ sumew,
    const int* __restrict__ rowptr, float* __restrict__ x1,
    ushort* __restrict__ x1b, int N) {
    int lane = threadIdx.x & 63;
    int strip = blockIdx.x * 4 + (threadIdx.x >> 6);
    int nstrips = (N + 15) >> 4;
    if (strip >= nstrips) return;
    int row0 = strip << 4;
    int arow = row0 + (lane & 15);
    if (arow >= N) arow = N - 1;
    int kg = (lane >> 4) << 3;
    int bcol = lane & 15;

    bf16x8 af[4];
#pragma unroll
    for (int kc = 0; kc < 4; ++kc)
        af[kc] = *(const bf16x8*)(aggb + (size_t)arow * DF + kc * 32 + kg);

    f32x4 acc[8];
#pragma unroll
    for (int nt = 0; nt < 8; ++nt) {
        f32x4 a = {0.f, 0.f, 0.f, 0.f};
#pragma unroll
        for (int kc = 0; kc < 4; ++kc) {
            bf16x8 bf = *(const bf16x8*)(Wt + (size_t)(nt * 16 + bcol) * DF + kc * 32 + kg);
            a = __builtin_amdgcn_mfma_f32_16x16x32_bf16(af[kc], bf, a, 0, 0, 0);
        }
        acc[nt] = a;
    }

#pragma unroll
    for (int r = 0; r < 4; ++r) {
        int R = row0 + ((lane >> 4) << 2) + r;
        if (R >= N) continue;
        int deg = rowptr[R + 1] - rowptr[R];
        float wb = sumew[R] / fmaxf((float)deg, 1.0f);
#pragma unroll
        for (int nt = 0; nt < 8; ++nt) {
            int col = nt * 16 + bcol;
            float v = acc[nt][r] + bl[col] * wb;
            x1[(size_t)R * DF + col] = v;
            x1b[(size_t)R * DF + col] = (ushort)f2bf(v);
        }
    }
}

__device__ __forceinline__ float gelu_exact(float v) {
    return 0.5f * v * (1.0f + erff(v * 0.70710678118654752440f));
}

__global__ __launch_bounds__(256) void mm2_k(
    const ushort* __restrict__ aggb, const ushort* __restrict__ Wt,
    const float* __restrict__ bl, const float* __restrict__ sumew,
    const int* __restrict__ rowptr, const float* __restrict__ x1,
    const float* __restrict__ gamma, const float* __restrict__ beta,
    float* __restrict__ out, int N) {
    int lane = threadIdx.x & 63;
    int strip = blockIdx.x * 4 + (threadIdx.x >> 6);
    int nstrips = (N + 15) >> 4;
    if (strip >= nstrips) return;
    int row0 = strip << 4;
    int arow = row0 + (lane & 15);
    if (arow >= N) arow = N - 1;
    int kg = (lane >> 4) << 3;
    int bcol = lane & 15;

    bf16x8 af[4];
#pragma unroll
    for (int kc = 0; kc < 4; ++kc)
        af[kc] = *(const bf16x8*)(aggb + (size_t)arow * DF + kc * 32 + kg);

    f32x4 acc[8];
#pragma unroll
    for (int nt = 0; nt < 8; ++nt) {
        f32x4 a = {0.f, 0.f, 0.f, 0.f};
#pragma unroll
        for (int kc = 0; kc < 4; ++kc) {
            bf16x8 bf = *(const bf16x8*)(Wt + (size_t)(nt * 16 + bcol) * DF + kc * 32 + kg);
            a = __builtin_amdgcn_mfma_f32_16x16x32_bf16(af[kc], bf, a, 0, 0, 0);
        }
        acc[nt] = a;
    }

#pragma unroll
    for (int r = 0; r < 4; ++r) {
        int R = row0 + ((lane >> 4) << 2) + r;
        if (R >= N) continue;
        int deg = rowptr[R + 1] - rowptr[R];
        float wb = (sumew[R] + 1.0f) / (float)(deg + 1);
        float pre[8];
        float s = 0.f;
#pragma unroll
        for (int nt = 0; nt < 8; ++nt) {
            int col = nt * 16 + bcol;
            pre[nt] = acc[nt][r] + bl[col] * wb + x1[(size_t)R * DF + col];
            s += pre[nt];
        }
        s += __shfl_xor(s, 1);
        s += __shfl_xor(s, 2);
        s += __shfl_xor(s, 4);
        s += __shfl_xor(s, 8);
        float mu = s * (1.0f / 128.0f);
        float vs = 0.f;
#pragma unroll
        for (int nt = 0; nt < 8; ++nt) {
            float d = pre[nt] - mu;
            vs += d * d;
        }
        vs += __shfl_xor(vs, 1);
        vs += __shfl_xor(vs, 2);
        vs += __shfl_xor(vs, 4);
        vs += __shfl_xor(vs, 8);
        float rstd = rsqrtf(vs * (1.0f / 128.0f) + 1e-5f);
#pragma unroll
        for (int nt = 0; nt < 8; ++nt) {
            int col = nt * 16 + bcol;
            float y = (pre[nt] - mu) * rstd * gamma[col] + beta[col];
            out[(size_t)R * DF + col] = gelu_exact(y);
        }
    }
}

// ---------------- launch ----------------

extern "C" void kernel_launch(void* const* d_in, const int* in_sizes, int n_in,
                              void* d_out, int out_size, void* d_ws, size_t ws_size,
                              hipStream_t stream) {
    const float* x     = (const float*)d_in[0];
    const int*   ei    = (const int*)d_in[1];
    const float* ew    = (const float*)d_in[2];
    const float* Wl1   = (const float*)d_in[3];
    const float* bl1   = (const float*)d_in[4];
    const float* Wl2   = (const float*)d_in[5];
    const float* bl2   = (const float*)d_in[6];
    const float* gamma = (const float*)d_in[7];
    const float* beta  = (const float*)d_in[8];
    float* out = (float*)d_out;

    int N = in_sizes[0] / DF;
    int E = in_sizes[2];
    const int* src = ei;
    const int* dst = ei + E;

    char* ws = (char*)d_ws;
    size_t off = 0;
    auto alloc = [&](size_t bytes) -> void* {
        void* p = ws + off;
        off += (bytes + 255) & ~(size_t)255;
        return p;
    };
    int*    cnt     = (int*)alloc((size_t)N * 4);
    float*  sumew   = (float*)alloc((size_t)N * 4);
    int*    rowptr  = (int*)alloc((size_t)(N + 1) * 4);
    int*    cursor  = (int*)alloc((size_t)N * 4);
    int*    bsum    = (int*)alloc(1024);
    int*    boff    = (int*)alloc(1024);
    int2*   adj     = (int2*)alloc((size_t)E * 8);
    uint*   xb      = (uint*)alloc((size_t)N * DF * 2);
    uint*   aggb    = (uint*)alloc((size_t)N * DF * 2);
    float*  x1      = (float*)alloc((size_t)N * DF * 4);
    ushort* x1b     = (ushort*)alloc((size_t)N * DF * 2);
    uint*   Wt1     = (uint*)alloc((size_t)DF * DF * 2);
    uint*   Wt2     = (uint*)alloc((size_t)DF * DF * 2);

    hipMemsetAsync(cnt, 0, (size_t)N * 4, stream);

    int n4 = N * DF / 4;
    int cvtxB = (n4 + 255) / 256;
    int histB = (E + 1023) / 1024;
    hipLaunchKernelGGL(prep_k, dim3(cvtxB + 64 + histB), dim3(256), 0, stream,
                       x, xb, n4, Wl1, Wl2, Wt1, Wt2, dst, cnt, E, cvtxB);

    int nb_scan = (N + 1023) / 1024;
    hipLaunchKernelGGL(partial_k, dim3(nb_scan), dim3(256), 0, stream, cnt, bsum, N);
    hipLaunchKernelGGL(scanb_k, dim3(1), dim3(256), 0, stream, bsum, boff, rowptr, nb_scan, N);
    hipLaunchKernelGGL(rowfill_k, dim3(nb_scan), dim3(256), 0, stream, cnt, boff, rowptr, cursor, N);
    int eb = (E + 255) / 256;
    hipLaunchKernelGGL(fill_k, dim3(eb), dim3(256), 0, stream, src, dst, ew, cursor, adj, E);

    int nb = (N * 64 + 255) / 256;
    int nstrips = (N + 15) / 16;
    int mb = (nstrips + 3) / 4;

    hipLaunchKernelGGL(agg_k<0>, dim3(nb), dim3(256), 0, stream, xb, rowptr, adj, aggb, sumew, N);
    hipLaunchKernelGGL(mm1_k, dim3(mb), dim3(256), 0, stream,
                       (const ushort*)aggb, (const ushort*)Wt1, bl1, sumew, rowptr, x1, x1b, N);
    hipLaunchKernelGGL(agg_k<1>, dim3(nb), dim3(256), 0, stream, (const uint*)x1b, rowptr, adj, aggb, sumew, N);
    hipLaunchKernelGGL(mm2_k, dim3(mb), dim3(256), 0, stream,
                       (const ushort*)aggb, (const ushort*)Wt2, bl2, sumew, rowptr, x1, gamma, beta, out, N);
}

// Round 6
// 204.549 us; speedup vs baseline: 3.3535x; 1.1158x over previous
//
#include <hip/hip_runtime.h>
#include <math.h>

#define DF 128
#define NPB 256   // nodes per bucket (partition path)
#define EPB 4096  // edges per passA block
#define CAP 7168  // passB LDS image capacity (edges)

typedef __attribute__((ext_vector_type(8))) short bf16x8;
typedef __attribute__((ext_vector_type(4))) float f32x4;

__device__ __forceinline__ float bf2f(uint u) {
    union { uint i; float f; } v; v.i = u << 16; return v.f;
}
__device__ __forceinline__ uint f2bf(float f) {  // round-to-nearest-even
    union { float f; uint i; } v; v.f = f;
    return (v.i + 0x7fffu + ((v.i >> 16) & 1u)) >> 16;
}

// ---------------- fused prep: cvt_x (float4) + cvtW + hist (cnt only, int4) ----------------

__global__ void prep_k(const float* __restrict__ x, uint* __restrict__ xb, int n4,
                       const float* __restrict__ W1, const float* __restrict__ W2,
                       uint* __restrict__ Wt1, uint* __restrict__ Wt2,
                       const int* __restrict__ dst, int* __restrict__ cnt, int E,
                       int cvtxB) {
    int b = blockIdx.x;
    if (b < cvtxB) {
        int i = b * 256 + threadIdx.x;
        if (i < n4) {
            float4 v = ((const float4*)x)[i];
            uint2 o;
            o.x = f2bf(v.x) | (f2bf(v.y) << 16);
            o.y = f2bf(v.z) | (f2bf(v.w) << 16);
            ((uint2*)xb)[i] = o;
        }
    } else if (b < cvtxB + 64) {
        int i = (b - cvtxB) * 256 + threadIdx.x;  // 0..16383
        const float* W = (i < 8192) ? W1 : W2;
        uint* Wt = (i < 8192) ? Wt1 : Wt2;
        int j = i & 8191;
        int n = j >> 6, kk = j & 63;
        Wt[n * 64 + kk] = f2bf(W[(2 * kk) * DF + n]) | (f2bf(W[(2 * kk + 1) * DF + n]) << 16);
    } else {
        int e0 = ((b - cvtxB - 64) * 256 + threadIdx.x) * 4;
        if (e0 + 4 <= E) {
            int4 d = *(const int4*)(dst + e0);
            atomicAdd(&cnt[d.x], 1);
            atomicAdd(&cnt[d.y], 1);
            atomicAdd(&cnt[d.z], 1);
            atomicAdd(&cnt[d.w], 1);
        } else {
            for (int j = e0; j < E; ++j) atomicAdd(&cnt[dst[j]], 1);
        }
    }
}

// ---------------- parallel scan (3 stages) ----------------

__global__ void partial_k(const int* __restrict__ cnt, int* __restrict__ bsum, int N) {
    int t = threadIdx.x, b = blockIdx.x;
    int base = b * 1024 + t * 4;
    int s = 0;
    if (base + 4 <= N) {
        int4 v = *(const int4*)(cnt + base);
        s = v.x + v.y + v.z + v.w;
    } else {
        for (int j = 0; j < 4; ++j)
            if (base + j < N) s += cnt[base + j];
    }
    __shared__ int sm[256];
    sm[t] = s;
    __syncthreads();
    for (int off = 128; off > 0; off >>= 1) {
        if (t < off) sm[t] += sm[t + off];
        __syncthreads();
    }
    if (t == 0) bsum[b] = sm[0];
}

__global__ void scanb_k(const int* __restrict__ bsum, int* __restrict__ boff,
                        int* __restrict__ rowptr, int nb, int N) {
    int t = threadIdx.x;
    int v = (t < nb) ? bsum[t] : 0;
    __shared__ int sm[256];
    sm[t] = v;
    __syncthreads();
    for (int off = 1; off < 256; off <<= 1) {
        int u = (t >= off) ? sm[t - off] : 0;
        __syncthreads();
        sm[t] += u;
        __syncthreads();
    }
    if (t < nb) boff[t] = sm[t] - v;
    if (t == 255) rowptr[N] = sm[255];
}

__global__ void rowfill_k(const int* __restrict__ cnt, const int* __restrict__ boff,
                          int* __restrict__ rowptr, int* __restrict__ cursor, int N) {
    int t = threadIdx.x, b = blockIdx.x;
    int base = b * 1024 + t * 4;
    int c0 = 0, c1 = 0, c2 = 0, c3 = 0;
    if (base + 4 <= N) {
        int4 v = *(const int4*)(cnt + base);
        c0 = v.x; c1 = v.y; c2 = v.z; c3 = v.w;
    } else {
        if (base + 0 < N) c0 = cnt[base + 0];
        if (base + 1 < N) c1 = cnt[base + 1];
        if (base + 2 < N) c2 = cnt[base + 2];
        if (base + 3 < N) c3 = cnt[base + 3];
    }
    int s = c0 + c1 + c2 + c3;
    __shared__ int sm[256];
    sm[t] = s;
    __syncthreads();
    for (int off = 1; off < 256; off <<= 1) {
        int u = (t >= off) ? sm[t - off] : 0;
        __syncthreads();
        sm[t] += u;
        __syncthreads();
    }
    int run = boff[b] + sm[t] - s;
    if (base + 0 < N) { rowptr[base + 0] = run; cursor[base + 0] = run; run += c0; }
    if (base + 1 < N) { rowptr[base + 1] = run; cursor[base + 1] = run; run += c1; }
    if (base + 2 < N) { rowptr[base + 2] = run; cursor[base + 2] = run; run += c2; }
    if (base + 3 < N) { rowptr[base + 3] = run; cursor[base + 3] = run; run += c3; }
}

// per-bucket staging cursors: gcur[b] = rowptr[b*NPB]
__global__ void gcinit_k(const int* __restrict__ rowptr, int* __restrict__ gcur, int nbk) {
    int b = threadIdx.x;
    if (b < nbk) gcur[b] = rowptr[b * NPB];
}

// ---------------- partitioned CSR fill ----------------
// Pass A: block-local counting sort of a 4096-edge chunk by dst bucket, write
// per-bucket runs into staging (bucket-major CSR layout). ~21-edge (168B) runs.
__global__ __launch_bounds__(256) void passA_k(
    const int* __restrict__ src, const int* __restrict__ dst,
    const float* __restrict__ ew, int* __restrict__ gcur,
    uint2* __restrict__ stage, int E) {
    __shared__ int lhist[256];
    __shared__ int lscan[256];
    __shared__ int lcur[256];
    __shared__ int gbase[256];
    __shared__ unsigned char lbk[EPB];
    __shared__ uint2 img[EPB];
    int t = threadIdx.x;
    int base = blockIdx.x * EPB;
    int cnt = min(EPB, E - base);
    lhist[t] = 0;
    __syncthreads();
    uint ps[16], pw[16];
    int pb[16];
#pragma unroll
    for (int k = 0; k < 16; ++k) {
        int i = base + k * 256 + t;
        pb[k] = -1;
        if (i < E) {
            int d = dst[i];
            int bk = d >> 8;  // NPB=256
            pb[k] = bk;
            ps[k] = (uint)src[i] | ((uint)(d & 255) << 23);
            pw[k] = __float_as_uint(ew[i]);
            atomicAdd(&lhist[bk], 1);
        }
    }
    __syncthreads();
    int v = lhist[t];
    lscan[t] = v;
    __syncthreads();
    for (int off = 1; off < 256; off <<= 1) {
        int u = (t >= off) ? lscan[t - off] : 0;
        __syncthreads();
        lscan[t] += u;
        __syncthreads();
    }
    lcur[t] = lscan[t] - v;  // exclusive prefix
    if (v > 0) gbase[t] = atomicAdd(&gcur[t], v);
    __syncthreads();
#pragma unroll
    for (int k = 0; k < 16; ++k) {
        if (pb[k] >= 0) {
            int p = atomicAdd(&lcur[pb[k]], 1);
            img[p] = make_uint2(ps[k], pw[k]);
            lbk[p] = (unsigned char)pb[k];
        }
    }
    __syncthreads();
    for (int i = t; i < cnt; i += 256) {
        int bk = lbk[i];
        stage[gbase[bk] + (i - (lscan[bk] - lhist[bk]))] = img[i];
    }
}

// Pass B: one block per bucket; scatter staged edges into LDS image via LDS
// cursors, then copy out coalesced.
__global__ __launch_bounds__(256) void passB_k(
    const uint2* __restrict__ stage, const int* __restrict__ rowptr,
    int* __restrict__ cursor, int2* __restrict__ adj, int N) {
    __shared__ int lcur[256];
    __shared__ uint2 img[CAP];
    int t = threadIdx.x;
    int b = blockIdx.x;
    int nb0 = b * NPB;
    int nn = min(NPB, N - nb0);
    int ebase = rowptr[nb0];
    int ecnt = rowptr[nb0 + nn] - ebase;
    if (t < nn) lcur[t] = rowptr[nb0 + t] - ebase;
    __syncthreads();
    if (ecnt <= CAP) {
        for (int i = t; i < ecnt; i += 256) {
            uint2 e = stage[ebase + i];
            int dl = (e.x >> 23) & 255;
            int p = atomicAdd(&lcur[dl], 1);
            img[p] = make_uint2(e.x & 0x7fffffu, e.y);
        }
        __syncthreads();
        for (int i = t; i < ecnt; i += 256) {
            uint2 e = img[i];
            adj[ebase + i] = make_int2((int)e.x, (int)e.y);
        }
    } else {  // statistically unreachable; correctness fallback
        for (int i = t; i < ecnt; i += 256) {
            uint2 e = stage[ebase + i];
            int dl = (e.x >> 23) & 255;
            int p = atomicAdd(&cursor[nb0 + dl], 1);
            adj[p] = make_int2((int)(e.x & 0x7fffffu), (int)e.y);
        }
    }
}

// generic fallback fill (N > 65536 path)
__global__ void fill_k(const int* __restrict__ src, const int* __restrict__ dst,
                       const float* __restrict__ ew, int* __restrict__ cursor,
                       int2* __restrict__ adj, int E) {
    int i = blockIdx.x * blockDim.x + threadIdx.x;
    if (i < E) {
        int p = atomicAdd(&cursor[dst[i]], 1);
        int2 e;
        e.x = src[i];
        e.y = __float_as_int(ew[i]);
        adj[p] = e;
    }
}

// ---------------- aggregation (pull, one wave per node, packed adj, 8-wide MLP) ----------------

template <int SELF>
__global__ void agg_k(const uint* __restrict__ xb, const int* __restrict__ rowptr,
                      const int2* __restrict__ adj, uint* __restrict__ aggb,
                      float* __restrict__ sumew, int N) {
    int wid = (blockIdx.x * blockDim.x + threadIdx.x) >> 6;
    int lane = threadIdx.x & 63;
    if (wid >= N) return;
    int lo = rowptr[wid], hi = rowptr[wid + 1];
    float a0 = 0.f, a1 = 0.f, ws = 0.f;
    if (SELF) {
        uint v = xb[(size_t)wid * 64 + lane];
        a0 = bf2f(v & 0xffffu);
        a1 = bf2f(v >> 16);
    }
    for (int base = lo; base < hi; base += 64) {
        int p = base + lane;
        int sidx = 0; float wv = 0.f;
        if (p < hi) {
            int2 e = adj[p];
            sidx = e.x;
            wv = __int_as_float(e.y);
        }
        ws += wv;
        int cnt = min(hi - base, 64);
        int j = 0;
        for (; j + 8 <= cnt; j += 8) {
            int s0 = __shfl(sidx, j),     s1 = __shfl(sidx, j + 1);
            int s2 = __shfl(sidx, j + 2), s3 = __shfl(sidx, j + 3);
            int s4 = __shfl(sidx, j + 4), s5 = __shfl(sidx, j + 5);
            int s6 = __shfl(sidx, j + 6), s7 = __shfl(sidx, j + 7);
            float w0 = __shfl(wv, j),     w1 = __shfl(wv, j + 1);
            float w2 = __shfl(wv, j + 2), w3 = __shfl(wv, j + 3);
            float w4 = __shfl(wv, j + 4), w5 = __shfl(wv, j + 5);
            float w6 = __shfl(wv, j + 6), w7 = __shfl(wv, j + 7);
            uint v0 = xb[(size_t)s0 * 64 + lane];
            uint v1 = xb[(size_t)s1 * 64 + lane];
            uint v2 = xb[(size_t)s2 * 64 + lane];
            uint v3 = xb[(size_t)s3 * 64 + lane];
            uint v4 = xb[(size_t)s4 * 64 + lane];
            uint v5 = xb[(size_t)s5 * 64 + lane];
            uint v6 = xb[(size_t)s6 * 64 + lane];
            uint v7 = xb[(size_t)s7 * 64 + lane];
            a0 += w0 * bf2f(v0 & 0xffffu); a1 += w0 * bf2f(v0 >> 16);
            a0 += w1 * bf2f(v1 & 0xffffu); a1 += w1 * bf2f(v1 >> 16);
            a0 += w2 * bf2f(v2 & 0xffffu); a1 += w2 * bf2f(v2 >> 16);
            a0 += w3 * bf2f(v3 & 0xffffu); a1 += w3 * bf2f(v3 >> 16);
            a0 += w4 * bf2f(v4 & 0xffffu); a1 += w4 * bf2f(v4 >> 16);
            a0 += w5 * bf2f(v5 & 0xffffu); a1 += w5 * bf2f(v5 >> 16);
            a0 += w6 * bf2f(v6 & 0xffffu); a1 += w6 * bf2f(v6 >> 16);
            a0 += w7 * bf2f(v7 & 0xffffu); a1 += w7 * bf2f(v7 >> 16);
        }
        for (; j < cnt; ++j) {
            int sj = __shfl(sidx, j);
            float wj = __shfl(wv, j);
            uint v = xb[(size_t)sj * 64 + lane];
            a0 += wj * bf2f(v & 0xffffu);
            a1 += wj * bf2f(v >> 16);
        }
    }
    if (!SELF) {
        ws += __shfl_xor(ws, 1);
        ws += __shfl_xor(ws, 2);
        ws += __shfl_xor(ws, 4);
        ws += __shfl_xor(ws, 8);
        ws += __shfl_xor(ws, 16);
        ws += __shfl_xor(ws, 32);
        if (lane == 0) sumew[wid] = ws;
    }
    float inv = SELF ? 1.0f / (float)(hi - lo + 1)
                     : 1.0f / fmaxf((float)(hi - lo), 1.0f);
    aggb[(size_t)wid * 64 + lane] = f2bf(a0 * inv) | (f2bf(a1 * inv) << 16);
}

// ---------------- MFMA GEMMs: one wave per 16-row strip ----------------
// A frag: row=lane&15, k=(lane>>4)*8+j ; B frag: col=lane&15, same k
// D: col=lane&15, row=(lane>>4)*4+reg   [m89-verified]

__global__ __launch_bounds__(256) void mm1_k(
    const ushort* __restrict__ aggb, const ushort* __restrict__ Wt,
    const float* __restrict__ bl, const float* __restrict__ sumew,
    const int* __restrict__ rowptr, ushort* __restrict__ x1b, int N) {
    int lane = threadIdx.x & 63;
    int strip = blockIdx.x * 4 + (threadIdx.x >> 6);
    int nstrips = (N + 15) >> 4;
    if (strip >= nstrips) return;
    int row0 = strip << 4;
    int arow = row0 + (lane & 15);
    if (arow >= N) arow = N - 1;
    int kg = (lane >> 4) << 3;
    int bcol = lane & 15;

    bf16x8 af[4];
#pragma unroll
    for (int kc = 0; kc < 4; ++kc)
        af[kc] = *(const bf16x8*)(aggb + (size_t)arow * DF + kc * 32 + kg);

    f32x4 acc[8];
#pragma unroll
    for (int nt = 0; nt < 8; ++nt) {
        f32x4 a = {0.f, 0.f, 0.f, 0.f};
#pragma unroll
        for (int kc = 0; kc < 4; ++kc) {
            bf16x8 bf = *(const bf16x8*)(Wt + (size_t)(nt * 16 + bcol) * DF + kc * 32 + kg);
            a = __builtin_amdgcn_mfma_f32_16x16x32_bf16(af[kc], bf, a, 0, 0, 0);
        }
        acc[nt] = a;
    }

#pragma unroll
    for (int r = 0; r < 4; ++r) {
        int R = row0 + ((lane >> 4) << 2) + r;
        if (R >= N) continue;
        int deg = rowptr[R + 1] - rowptr[R];
        float wb = sumew[R] / fmaxf((float)deg, 1.0f);
#pragma unroll
        for (int nt = 0; nt < 8; ++nt) {
            int col = nt * 16 + bcol;
            x1b[(size_t)R * DF + col] = (ushort)f2bf(acc[nt][r] + bl[col] * wb);
        }
    }
}

__device__ __forceinline__ float gelu_exact(float v) {
    return 0.5f * v * (1.0f + erff(v * 0.70710678118654752440f));
}

__global__ __launch_bounds__(256) void mm2_k(
    const ushort* __restrict__ aggb, const ushort* __restrict__ Wt,
    const float* __restrict__ bl, const float* __restrict__ sumew,
    const int* __restrict__ rowptr, const ushort* __restrict__ x1b,
    const float* __restrict__ gamma, const float* __restrict__ beta,
    float* __restrict__ out, int N) {
    int lane = threadIdx.x & 63;
    int strip = blockIdx.x * 4 + (threadIdx.x >> 6);
    int nstrips = (N + 15) >> 4;
    if (strip >= nstrips) return;
    int row0 = strip << 4;
    int arow = row0 + (lane & 15);
    if (arow >= N) arow = N - 1;
    int kg = (lane >> 4) << 3;
    int bcol = lane & 15;

    bf16x8 af[4];
#pragma unroll
    for (int kc = 0; kc < 4; ++kc)
        af[kc] = *(const bf16x8*)(aggb + (size_t)arow * DF + kc * 32 + kg);

    f32x4 acc[8];
#pragma unroll
    for (int nt = 0; nt < 8; ++nt) {
        f32x4 a = {0.f, 0.f, 0.f, 0.f};
#pragma unroll
        for (int kc = 0; kc < 4; ++kc) {
            bf16x8 bf = *(const bf16x8*)(Wt + (size_t)(nt * 16 + bcol) * DF + kc * 32 + kg);
            a = __builtin_amdgcn_mfma_f32_16x16x32_bf16(af[kc], bf, a, 0, 0, 0);
        }
        acc[nt] = a;
    }

#pragma unroll
    for (int r = 0; r < 4; ++r) {
        int R = row0 + ((lane >> 4) << 2) + r;
        if (R >= N) continue;
        int deg = rowptr[R + 1] - rowptr[R];
        float wb = (sumew[R] + 1.0f) / (float)(deg + 1);
        float pre[8];
        float s = 0.f;
#pragma unroll
        for (int nt = 0; nt < 8; ++nt) {
            int col = nt * 16 + bcol;
            pre[nt] = acc[nt][r] + bl[col] * wb + bf2f(x1b[(size_t)R * DF + col]);
            s += pre[nt];
        }
        s += __shfl_xor(s, 1);
        s += __shfl_xor(s, 2);
        s += __shfl_xor(s, 4);
        s += __shfl_xor(s, 8);
        float mu = s * (1.0f / 128.0f);
        float vs = 0.f;
#pragma unroll
        for (int nt = 0; nt < 8; ++nt) {
            float d = pre[nt] - mu;
            vs += d * d;
        }
        vs += __shfl_xor(vs, 1);
        vs += __shfl_xor(vs, 2);
        vs += __shfl_xor(vs, 4);
        vs += __shfl_xor(vs, 8);
        float rstd = rsqrtf(vs * (1.0f / 128.0f) + 1e-5f);
#pragma unroll
        for (int nt = 0; nt < 8; ++nt) {
            int col = nt * 16 + bcol;
            float y = (pre[nt] - mu) * rstd * gamma[col] + beta[col];
            out[(size_t)R * DF + col] = gelu_exact(y);
        }
    }
}

// ---------------- launch ----------------

extern "C" void kernel_launch(void* const* d_in, const int* in_sizes, int n_in,
                              void* d_out, int out_size, void* d_ws, size_t ws_size,
                              hipStream_t stream) {
    const float* x     = (const float*)d_in[0];
    const int*   ei    = (const int*)d_in[1];
    const float* ew    = (const float*)d_in[2];
    const float* Wl1   = (const float*)d_in[3];
    const float* bl1   = (const float*)d_in[4];
    const float* Wl2   = (const float*)d_in[5];
    const float* bl2   = (const float*)d_in[6];
    const float* gamma = (const float*)d_in[7];
    const float* beta  = (const float*)d_in[8];
    float* out = (float*)d_out;

    int N = in_sizes[0] / DF;
    int E = in_sizes[2];
    const int* src = ei;
    const int* dst = ei + E;

    char* ws = (char*)d_ws;
    size_t off = 0;
    auto alloc = [&](size_t bytes) -> void* {
        void* p = ws + off;
        off += (bytes + 255) & ~(size_t)255;
        return p;
    };
    int*    cnt     = (int*)alloc((size_t)N * 4);
    float*  sumew   = (float*)alloc((size_t)N * 4);
    int*    rowptr  = (int*)alloc((size_t)(N + 1) * 4);
    int*    cursor  = (int*)alloc((size_t)N * 4);
    int*    bsum    = (int*)alloc(1024);
    int*    boff    = (int*)alloc(1024);
    int*    gcur    = (int*)alloc(1024);
    int2*   adj     = (int2*)alloc((size_t)E * 8);
    uint2*  stage   = (uint2*)alloc((size_t)E * 8);
    uint*   xb      = (uint*)alloc((size_t)N * DF * 2);
    uint*   aggb    = (uint*)alloc((size_t)N * DF * 2);
    ushort* x1b     = (ushort*)alloc((size_t)N * DF * 2);
    uint*   Wt1     = (uint*)alloc((size_t)DF * DF * 2);
    uint*   Wt2     = (uint*)alloc((size_t)DF * DF * 2);

    hipMemsetAsync(cnt, 0, (size_t)N * 4, stream);

    int n4 = N * DF / 4;
    int cvtxB = (n4 + 255) / 256;
    int histB = (E + 1023) / 1024;
    hipLaunchKernelGGL(prep_k, dim3(cvtxB + 64 + histB), dim3(256), 0, stream,
                       x, xb, n4, Wl1, Wl2, Wt1, Wt2, dst, cnt, E, cvtxB);

    int nb_scan = (N + 1023) / 1024;
    hipLaunchKernelGGL(partial_k, dim3(nb_scan), dim3(256), 0, stream, cnt, bsum, N);
    hipLaunchKernelGGL(scanb_k, dim3(1), dim3(256), 0, stream, bsum, boff, rowptr, nb_scan, N);
    hipLaunchKernelGGL(rowfill_k, dim3(nb_scan), dim3(256), 0, stream, cnt, boff, rowptr, cursor, N);

    int nbk = (N + NPB - 1) / NPB;
    if (nbk <= 256) {  // partitioned fill (line-dense writes)
        hipLaunchKernelGGL(gcinit_k, dim3(1), dim3(256), 0, stream, rowptr, gcur, nbk);
        int ab = (E + EPB - 1) / EPB;
        hipLaunchKernelGGL(passA_k, dim3(ab), dim3(256), 0, stream, src, dst, ew, gcur, stage, E);
        hipLaunchKernelGGL(passB_k, dim3(nbk), dim3(256), 0, stream, stage, rowptr, cursor, adj, N);
    } else {
        int eb = (E + 255) / 256;
        hipLaunchKernelGGL(fill_k, dim3(eb), dim3(256), 0, stream, src, dst, ew, cursor, adj, E);
    }

    int nb = (N * 64 + 255) / 256;
    int nstrips = (N + 15) / 16;
    int mb = (nstrips + 3) / 4;

    hipLaunchKernelGGL(agg_k<0>, dim3(nb), dim3(256), 0, stream, xb, rowptr, adj, aggb, sumew, N);
    hipLaunchKernelGGL(mm1_k, dim3(mb), dim3(256), 0, stream,
                       (const ushort*)aggb, (const ushort*)Wt1, bl1, sumew, rowptr, x1b, N);
    hipLaunchKernelGGL(agg_k<1>, dim3(nb), dim3(256), 0, stream, (const uint*)x1b, rowptr, adj, aggb, sumew, N);
    hipLaunchKernelGGL(mm2_k, dim3(mb), dim3(256), 0, stream,
                       (const ushort*)aggb, (const ushort*)Wt2, bl2, sumew, rowptr, x1b, gamma, beta, out, N);
}

// Round 7
// 170.041 us; speedup vs baseline: 4.0341x; 1.2029x over previous
//
#include <hip/hip_runtime.h>
#include <math.h>

#define DF 128
#define NPB 256   // nodes per bucket (partition path)
#define EPB 4096  // edges per passA/hist block
#define CAP 7168  // passB LDS image capacity (edges)

typedef __attribute__((ext_vector_type(8))) short bf16x8;
typedef __attribute__((ext_vector_type(4))) float f32x4;

__device__ __forceinline__ float bf2f(uint u) {
    union { uint i; float f; } v; v.i = u << 16; return v.f;
}
__device__ __forceinline__ uint f2bf(float f) {  // round-to-nearest-even
    union { float f; uint i; } v; v.f = f;
    return (v.i + 0x7fffu + ((v.i >> 16) & 1u)) >> 16;
}

// ---------------- fused prep: cvt_x (float4) + cvtW + BUCKET hist (LDS-privatized) ----------------

__global__ void prep_k(const float* __restrict__ x, uint* __restrict__ xb, int n4,
                       const float* __restrict__ W1, const float* __restrict__ W2,
                       uint* __restrict__ Wt1, uint* __restrict__ Wt2,
                       const int* __restrict__ dst, int* __restrict__ bcnt, int E,
                       int cvtxB) {
    __shared__ int lh[256];
    int b = blockIdx.x;
    int t = threadIdx.x;
    if (b < cvtxB) {
        int i = b * 256 + t;
        if (i < n4) {
            float4 v = ((const float4*)x)[i];
            uint2 o;
            o.x = f2bf(v.x) | (f2bf(v.y) << 16);
            o.y = f2bf(v.z) | (f2bf(v.w) << 16);
            ((uint2*)xb)[i] = o;
        }
    } else if (b < cvtxB + 64) {
        int i = (b - cvtxB) * 256 + t;  // 0..16383
        const float* W = (i < 8192) ? W1 : W2;
        uint* Wt = (i < 8192) ? Wt1 : Wt2;
        int j = i & 8191;
        int n = j >> 6, kk = j & 63;
        Wt[n * 64 + kk] = f2bf(W[(2 * kk) * DF + n]) | (f2bf(W[(2 * kk + 1) * DF + n]) << 16);
    } else {
        // bucket-level histogram: EPB edges per block, LDS bins, 256 global atomics
        int base = (b - cvtxB - 64) * EPB;
        lh[t] = 0;
        __syncthreads();
#pragma unroll
        for (int k = 0; k < EPB / 256; ++k) {
            int i = base + k * 256 + t;
            if (i < E) atomicAdd(&lh[dst[i] >> 8], 1);
        }
        __syncthreads();
        int v = lh[t];
        if (v) atomicAdd(&bcnt[t], v);
    }
}

// single block: exclusive scan of 256 bucket counts -> bkoff[257], init gcur
__global__ void bscan_k(const int* __restrict__ bcnt, int* __restrict__ bkoff,
                        int* __restrict__ gcur) {
    int t = threadIdx.x;
    int v = bcnt[t];
    __shared__ int sm[256];
    sm[t] = v;
    __syncthreads();
    for (int off = 1; off < 256; off <<= 1) {
        int u = (t >= off) ? sm[t - off] : 0;
        __syncthreads();
        sm[t] += u;
        __syncthreads();
    }
    int ex = sm[t] - v;
    bkoff[t] = ex;
    gcur[t] = ex;
    if (t == 255) bkoff[256] = sm[255];
}

// ---------------- partitioned CSR fill ----------------
// Pass A: block-local counting sort of a 4096-edge chunk by dst bucket, write
// per-bucket runs into staging (bucket-major layout). ~21-edge (168B) runs.
__global__ __launch_bounds__(256) void passA_k(
    const int* __restrict__ src, const int* __restrict__ dst,
    const float* __restrict__ ew, int* __restrict__ gcur,
    uint2* __restrict__ stage, int E) {
    __shared__ int lhist[256];
    __shared__ int lscan[256];
    __shared__ int lcur[256];
    __shared__ int gbase[256];
    __shared__ unsigned char lbk[EPB];
    __shared__ uint2 img[EPB];
    int t = threadIdx.x;
    int base = blockIdx.x * EPB;
    int cnt = min(EPB, E - base);
    lhist[t] = 0;
    __syncthreads();
    uint ps[16], pw[16];
    int pb[16];
#pragma unroll
    for (int k = 0; k < 16; ++k) {
        int i = base + k * 256 + t;
        pb[k] = -1;
        if (i < E) {
            int d = dst[i];
            int bk = d >> 8;  // NPB=256
            pb[k] = bk;
            ps[k] = (uint)src[i] | ((uint)(d & 255) << 23);
            pw[k] = __float_as_uint(ew[i]);
            atomicAdd(&lhist[bk], 1);
        }
    }
    __syncthreads();
    int v = lhist[t];
    lscan[t] = v;
    __syncthreads();
    for (int off = 1; off < 256; off <<= 1) {
        int u = (t >= off) ? lscan[t - off] : 0;
        __syncthreads();
        lscan[t] += u;
        __syncthreads();
    }
    lcur[t] = lscan[t] - v;  // exclusive prefix
    if (v > 0) gbase[t] = atomicAdd(&gcur[t], v);
    __syncthreads();
#pragma unroll
    for (int k = 0; k < 16; ++k) {
        if (pb[k] >= 0) {
            int p = atomicAdd(&lcur[pb[k]], 1);
            img[p] = make_uint2(ps[k], pw[k]);
            lbk[p] = (unsigned char)pb[k];
        }
    }
    __syncthreads();
    for (int i = t; i < cnt; i += 256) {
        int bk = lbk[i];
        stage[gbase[bk] + (i - (lscan[bk] - lhist[bk]))] = img[i];
    }
}

// Pass B: one block per bucket. Builds the node-level CSR locally (LDS
// histogram + scan -> rowptr), scatters staged edges into an LDS image,
// copies out coalesced.
__global__ __launch_bounds__(256) void passB_k(
    const uint2* __restrict__ stage, const int* __restrict__ bkoff,
    int* __restrict__ rowptr, int* __restrict__ cursor,
    int2* __restrict__ adj, int N, int nbk) {
    __shared__ int lhist[256];
    __shared__ int lpre[256];
    __shared__ int lcur[256];
    __shared__ uint2 img[CAP];
    int t = threadIdx.x;
    int b = blockIdx.x;
    int nb0 = b * NPB;
    int nn = min(NPB, N - nb0);
    int ebase = bkoff[b];
    int ecnt = bkoff[b + 1] - ebase;
    lhist[t] = 0;
    __syncthreads();
    for (int i = t; i < ecnt; i += 256) {
        uint2 e = stage[ebase + i];
        atomicAdd(&lhist[(e.x >> 23) & 255], 1);
    }
    __syncthreads();
    int v = lhist[t];
    lpre[t] = v;
    __syncthreads();
    for (int off = 1; off < 256; off <<= 1) {
        int u = (t >= off) ? lpre[t - off] : 0;
        __syncthreads();
        lpre[t] += u;
        __syncthreads();
    }
    int myoff = lpre[t] - v;  // exclusive prefix within bucket
    lcur[t] = myoff;
    if (t < nn) {
        rowptr[nb0 + t] = ebase + myoff;
        cursor[nb0 + t] = ebase + myoff;
    }
    if (b == nbk - 1 && t == 0) rowptr[N] = ebase + ecnt;
    __syncthreads();
    if (ecnt <= CAP) {
        for (int i = t; i < ecnt; i += 256) {
            uint2 e = stage[ebase + i];
            int p = atomicAdd(&lcur[(e.x >> 23) & 255], 1);
            img[p] = make_uint2(e.x & 0x7fffffu, e.y);
        }
        __syncthreads();
        for (int i = t; i < ecnt; i += 256) {
            uint2 e = img[i];
            adj[ebase + i] = make_int2((int)e.x, (int)e.y);
        }
    } else {  // statistically unreachable; correctness fallback
        for (int i = t; i < ecnt; i += 256) {
            uint2 e = stage[ebase + i];
            int dl = (e.x >> 23) & 255;
            int p = atomicAdd(&cursor[nb0 + dl], 1);
            adj[p] = make_int2((int)(e.x & 0x7fffffu), (int)e.y);
        }
    }
}

// ---------------- generic fallback path (N > 65536 only) ----------------

__global__ void histn_k(const int* __restrict__ dst, int* __restrict__ cnt, int E) {
    int i = blockIdx.x * blockDim.x + threadIdx.x;
    if (i < E) atomicAdd(&cnt[dst[i]], 1);
}

__global__ void partial_k(const int* __restrict__ cnt, int* __restrict__ bsum, int N) {
    int t = threadIdx.x, b = blockIdx.x;
    int base = b * 1024 + t * 4;
    int s = 0;
    if (base + 4 <= N) {
        int4 v = *(const int4*)(cnt + base);
        s = v.x + v.y + v.z + v.w;
    } else {
        for (int j = 0; j < 4; ++j)
            if (base + j < N) s += cnt[base + j];
    }
    __shared__ int sm[256];
    sm[t] = s;
    __syncthreads();
    for (int off = 128; off > 0; off >>= 1) {
        if (t < off) sm[t] += sm[t + off];
        __syncthreads();
    }
    if (t == 0) bsum[b] = sm[0];
}

__global__ void scanb_k(const int* __restrict__ bsum, int* __restrict__ boff,
                        int* __restrict__ rowptr, int nb, int N) {
    int t = threadIdx.x;
    int v = (t < nb) ? bsum[t] : 0;
    __shared__ int sm[256];
    sm[t] = v;
    __syncthreads();
    for (int off = 1; off < 256; off <<= 1) {
        int u = (t >= off) ? sm[t - off] : 0;
        __syncthreads();
        sm[t] += u;
        __syncthreads();
    }
    if (t < nb) boff[t] = sm[t] - v;
    if (t == 255) rowptr[N] = sm[255];
}

__global__ void rowfill_k(const int* __restrict__ cnt, const int* __restrict__ boff,
                          int* __restrict__ rowptr, int* __restrict__ cursor, int N) {
    int t = threadIdx.x, b = blockIdx.x;
    int base = b * 1024 + t * 4;
    int c0 = 0, c1 = 0, c2 = 0, c3 = 0;
    if (base + 4 <= N) {
        int4 v = *(const int4*)(cnt + base);
        c0 = v.x; c1 = v.y; c2 = v.z; c3 = v.w;
    } else {
        if (base + 0 < N) c0 = cnt[base + 0];
        if (base + 1 < N) c1 = cnt[base + 1];
        if (base + 2 < N) c2 = cnt[base + 2];
        if (base + 3 < N) c3 = cnt[base + 3];
    }
    int s = c0 + c1 + c2 + c3;
    __shared__ int sm[256];
    sm[t] = s;
    __syncthreads();
    for (int off = 1; off < 256; off <<= 1) {
        int u = (t >= off) ? sm[t - off] : 0;
        __syncthreads();
        sm[t] += u;
        __syncthreads();
    }
    int run = boff[b] + sm[t] - s;
    if (base + 0 < N) { rowptr[base + 0] = run; cursor[base + 0] = run; run += c0; }
    if (base + 1 < N) { rowptr[base + 1] = run; cursor[base + 1] = run; run += c1; }
    if (base + 2 < N) { rowptr[base + 2] = run; cursor[base + 2] = run; run += c2; }
    if (base + 3 < N) { rowptr[base + 3] = run; cursor[base + 3] = run; run += c3; }
}

__global__ void fill_k(const int* __restrict__ src, const int* __restrict__ dst,
                       const float* __restrict__ ew, int* __restrict__ cursor,
                       int2* __restrict__ adj, int E) {
    int i = blockIdx.x * blockDim.x + threadIdx.x;
    if (i < E) {
        int p = atomicAdd(&cursor[dst[i]], 1);
        int2 e;
        e.x = src[i];
        e.y = __float_as_int(ew[i]);
        adj[p] = e;
    }
}

// ---------------- aggregation (pull, one wave per node, packed adj, 8-wide MLP) ----------------

template <int SELF>
__global__ void agg_k(const uint* __restrict__ xb, const int* __restrict__ rowptr,
                      const int2* __restrict__ adj, uint* __restrict__ aggb,
                      float* __restrict__ sumew, int N) {
    int wid = (blockIdx.x * blockDim.x + threadIdx.x) >> 6;
    int lane = threadIdx.x & 63;
    if (wid >= N) return;
    int lo = rowptr[wid], hi = rowptr[wid + 1];
    float a0 = 0.f, a1 = 0.f, ws = 0.f;
    if (SELF) {
        uint v = xb[(size_t)wid * 64 + lane];
        a0 = bf2f(v & 0xffffu);
        a1 = bf2f(v >> 16);
    }
    for (int base = lo; base < hi; base += 64) {
        int p = base + lane;
        int sidx = 0; float wv = 0.f;
        if (p < hi) {
            int2 e = adj[p];
            sidx = e.x;
            wv = __int_as_float(e.y);
        }
        ws += wv;
        int cnt = min(hi - base, 64);
        int j = 0;
        for (; j + 8 <= cnt; j += 8) {
            int s0 = __shfl(sidx, j),     s1 = __shfl(sidx, j + 1);
            int s2 = __shfl(sidx, j + 2), s3 = __shfl(sidx, j + 3);
            int s4 = __shfl(sidx, j + 4), s5 = __shfl(sidx, j + 5);
            int s6 = __shfl(sidx, j + 6), s7 = __shfl(sidx, j + 7);
            float w0 = __shfl(wv, j),     w1 = __shfl(wv, j + 1);
            float w2 = __shfl(wv, j + 2), w3 = __shfl(wv, j + 3);
            float w4 = __shfl(wv, j + 4), w5 = __shfl(wv, j + 5);
            float w6 = __shfl(wv, j + 6), w7 = __shfl(wv, j + 7);
            uint v0 = xb[(size_t)s0 * 64 + lane];
            uint v1 = xb[(size_t)s1 * 64 + lane];
            uint v2 = xb[(size_t)s2 * 64 + lane];
            uint v3 = xb[(size_t)s3 * 64 + lane];
            uint v4 = xb[(size_t)s4 * 64 + lane];
            uint v5 = xb[(size_t)s5 * 64 + lane];
            uint v6 = xb[(size_t)s6 * 64 + lane];
            uint v7 = xb[(size_t)s7 * 64 + lane];
            a0 += w0 * bf2f(v0 & 0xffffu); a1 += w0 * bf2f(v0 >> 16);
            a0 += w1 * bf2f(v1 & 0xffffu); a1 += w1 * bf2f(v1 >> 16);
            a0 += w2 * bf2f(v2 & 0xffffu); a1 += w2 * bf2f(v2 >> 16);
            a0 += w3 * bf2f(v3 & 0xffffu); a1 += w3 * bf2f(v3 >> 16);
            a0 += w4 * bf2f(v4 & 0xffffu); a1 += w4 * bf2f(v4 >> 16);
            a0 += w5 * bf2f(v5 & 0xffffu); a1 += w5 * bf2f(v5 >> 16);
            a0 += w6 * bf2f(v6 & 0xffffu); a1 += w6 * bf2f(v6 >> 16);
            a0 += w7 * bf2f(v7 & 0xffffu); a1 += w7 * bf2f(v7 >> 16);
        }
        for (; j < cnt; ++j) {
            int sj = __shfl(sidx, j);
            float wj = __shfl(wv, j);
            uint v = xb[(size_t)sj * 64 + lane];
            a0 += wj * bf2f(v & 0xffffu);
            a1 += wj * bf2f(v >> 16);
        }
    }
    if (!SELF) {
        ws += __shfl_xor(ws, 1);
        ws += __shfl_xor(ws, 2);
        ws += __shfl_xor(ws, 4);
        ws += __shfl_xor(ws, 8);
        ws += __shfl_xor(ws, 16);
        ws += __shfl_xor(ws, 32);
        if (lane == 0) sumew[wid] = ws;
    }
    float inv = SELF ? 1.0f / (float)(hi - lo + 1)
                     : 1.0f / fmaxf((float)(hi - lo), 1.0f);
    aggb[(size_t)wid * 64 + lane] = f2bf(a0 * inv) | (f2bf(a1 * inv) << 16);
}

// ---------------- MFMA GEMMs: one wave per 16-row strip ----------------
// A frag: row=lane&15, k=(lane>>4)*8+j ; B frag: col=lane&15, same k
// D: col=lane&15, row=(lane>>4)*4+reg   [m89-verified]

__global__ __launch_bounds__(256) void mm1_k(
    const ushort* __restrict__ aggb, const ushort* __restrict__ Wt,
    const float* __restrict__ bl, const float* __restrict__ sumew,
    const int* __restrict__ rowptr, ushort* __restrict__ x1b, int N) {
    int lane = threadIdx.x & 63;
    int strip = blockIdx.x * 4 + (threadIdx.x >> 6);
    int nstrips = (N + 15) >> 4;
    if (strip >= nstrips) return;
    int row0 = strip << 4;
    int arow = row0 + (lane & 15);
    if (arow >= N) arow = N - 1;
    int kg = (lane >> 4) << 3;
    int bcol = lane & 15;

    bf16x8 af[4];
#pragma unroll
    for (int kc = 0; kc < 4; ++kc)
        af[kc] = *(const bf16x8*)(aggb + (size_t)arow * DF + kc * 32 + kg);

    f32x4 acc[8];
#pragma unroll
    for (int nt = 0; nt < 8; ++nt) {
        f32x4 a = {0.f, 0.f, 0.f, 0.f};
#pragma unroll
        for (int kc = 0; kc < 4; ++kc) {
            bf16x8 bf = *(const bf16x8*)(Wt + (size_t)(nt * 16 + bcol) * DF + kc * 32 + kg);
            a = __builtin_amdgcn_mfma_f32_16x16x32_bf16(af[kc], bf, a, 0, 0, 0);
        }
        acc[nt] = a;
    }

#pragma unroll
    for (int r = 0; r < 4; ++r) {
        int R = row0 + ((lane >> 4) << 2) + r;
        if (R >= N) continue;
        int deg = rowptr[R + 1] - rowptr[R];
        float wb = sumew[R] / fmaxf((float)deg, 1.0f);
#pragma unroll
        for (int nt = 0; nt < 8; ++nt) {
            int col = nt * 16 + bcol;
            x1b[(size_t)R * DF + col] = (ushort)f2bf(acc[nt][r] + bl[col] * wb);
        }
    }
}

__device__ __forceinline__ float gelu_exact(float v) {
    return 0.5f * v * (1.0f + erff(v * 0.70710678118654752440f));
}

__global__ __launch_bounds__(256) void mm2_k(
    const ushort* __restrict__ aggb, const ushort* __restrict__ Wt,
    const float* __restrict__ bl, const float* __restrict__ sumew,
    const int* __restrict__ rowptr, const ushort* __restrict__ x1b,
    const float* __restrict__ gamma, const float* __restrict__ beta,
    float* __restrict__ out, int N) {
    int lane = threadIdx.x & 63;
    int strip = blockIdx.x * 4 + (threadIdx.x >> 6);
    int nstrips = (N + 15) >> 4;
    if (strip >= nstrips) return;
    int row0 = strip << 4;
    int arow = row0 + (lane & 15);
    if (arow >= N) arow = N - 1;
    int kg = (lane >> 4) << 3;
    int bcol = lane & 15;

    bf16x8 af[4];
#pragma unroll
    for (int kc = 0; kc < 4; ++kc)
        af[kc] = *(const bf16x8*)(aggb + (size_t)arow * DF + kc * 32 + kg);

    f32x4 acc[8];
#pragma unroll
    for (int nt = 0; nt < 8; ++nt) {
        f32x4 a = {0.f, 0.f, 0.f, 0.f};
#pragma unroll
        for (int kc = 0; kc < 4; ++kc) {
            bf16x8 bf = *(const bf16x8*)(Wt + (size_t)(nt * 16 + bcol) * DF + kc * 32 + kg);
            a = __builtin_amdgcn_mfma_f32_16x16x32_bf16(af[kc], bf, a, 0, 0, 0);
        }
        acc[nt] = a;
    }

#pragma unroll
    for (int r = 0; r < 4; ++r) {
        int R = row0 + ((lane >> 4) << 2) + r;
        if (R >= N) continue;
        int deg = rowptr[R + 1] - rowptr[R];
        float wb = (sumew[R] + 1.0f) / (float)(deg + 1);
        float pre[8];
        float s = 0.f;
#pragma unroll
        for (int nt = 0; nt < 8; ++nt) {
            int col = nt * 16 + bcol;
            pre[nt] = acc[nt][r] + bl[col] * wb + bf2f(x1b[(size_t)R * DF + col]);
            s += pre[nt];
        }
        s += __shfl_xor(s, 1);
        s += __shfl_xor(s, 2);
        s += __shfl_xor(s, 4);
        s += __shfl_xor(s, 8);
        float mu = s * (1.0f / 128.0f);
        float vs = 0.f;
#pragma unroll
        for (int nt = 0; nt < 8; ++nt) {
            float d = pre[nt] - mu;
            vs += d * d;
        }
        vs += __shfl_xor(vs, 1);
        vs += __shfl_xor(vs, 2);
        vs += __shfl_xor(vs, 4);
        vs += __shfl_xor(vs, 8);
        float rstd = rsqrtf(vs * (1.0f / 128.0f) + 1e-5f);
#pragma unroll
        for (int nt = 0; nt < 8; ++nt) {
            int col = nt * 16 + bcol;
            float y = (pre[nt] - mu) * rstd * gamma[col] + beta[col];
            out[(size_t)R * DF + col] = gelu_exact(y);
        }
    }
}

// ---------------- launch ----------------

extern "C" void kernel_launch(void* const* d_in, const int* in_sizes, int n_in,
                              void* d_out, int out_size, void* d_ws, size_t ws_size,
                              hipStream_t stream) {
    const float* x     = (const float*)d_in[0];
    const int*   ei    = (const int*)d_in[1];
    const float* ew    = (const float*)d_in[2];
    const float* Wl1   = (const float*)d_in[3];
    const float* bl1   = (const float*)d_in[4];
    const float* Wl2   = (const float*)d_in[5];
    const float* bl2   = (const float*)d_in[6];
    const float* gamma = (const float*)d_in[7];
    const float* beta  = (const float*)d_in[8];
    float* out = (float*)d_out;

    int N = in_sizes[0] / DF;
    int E = in_sizes[2];
    const int* src = ei;
    const int* dst = ei + E;

    char* ws = (char*)d_ws;
    size_t off = 0;
    auto alloc = [&](size_t bytes) -> void* {
        void* p = ws + off;
        off += (bytes + 255) & ~(size_t)255;
        return p;
    };
    float*  sumew   = (float*)alloc((size_t)N * 4);
    int*    rowptr  = (int*)alloc((size_t)(N + 1) * 4);
    int*    cursor  = (int*)alloc((size_t)N * 4);
    int*    bcnt    = (int*)alloc(1024);
    int*    bkoff   = (int*)alloc(1040);
    int*    gcur    = (int*)alloc(1024);
    int*    bsum    = (int*)alloc(1024);
    int*    boff    = (int*)alloc(1024);
    int2*   adj     = (int2*)alloc((size_t)E * 8);
    uint2*  stage   = (uint2*)alloc((size_t)E * 8);
    uint*   xb      = (uint*)alloc((size_t)N * DF * 2);
    uint*   aggb    = (uint*)alloc((size_t)N * DF * 2);
    ushort* x1b     = (ushort*)alloc((size_t)N * DF * 2);
    uint*   Wt1     = (uint*)alloc((size_t)DF * DF * 2);
    uint*   Wt2     = (uint*)alloc((size_t)DF * DF * 2);
    int*    cnt     = (int*)alloc((size_t)N * 4);  // fallback path only

    int nbk = (N + NPB - 1) / NPB;
    int n4 = N * DF / 4;
    int cvtxB = (n4 + 255) / 256;
    int histB = (E + EPB - 1) / EPB;

    if (nbk <= 256) {
        hipMemsetAsync(bcnt, 0, 1024, stream);
        hipLaunchKernelGGL(prep_k, dim3(cvtxB + 64 + histB), dim3(256), 0, stream,
                           x, xb, n4, Wl1, Wl2, Wt1, Wt2, dst, bcnt, E, cvtxB);
        hipLaunchKernelGGL(bscan_k, dim3(1), dim3(256), 0, stream, bcnt, bkoff, gcur);
        hipLaunchKernelGGL(passA_k, dim3(histB), dim3(256), 0, stream, src, dst, ew, gcur, stage, E);
        hipLaunchKernelGGL(passB_k, dim3(nbk), dim3(256), 0, stream,
                           stage, bkoff, rowptr, cursor, adj, N, nbk);
    } else {  // generic fallback (not taken for this problem size)
        hipMemsetAsync(cnt, 0, (size_t)N * 4, stream);
        hipLaunchKernelGGL(prep_k, dim3(cvtxB + 64), dim3(256), 0, stream,
                           x, xb, n4, Wl1, Wl2, Wt1, Wt2, dst, bcnt, 0, cvtxB);
        int eb = (E + 255) / 256;
        hipLaunchKernelGGL(histn_k, dim3(eb), dim3(256), 0, stream, dst, cnt, E);
        int nb_scan = (N + 1023) / 1024;
        hipLaunchKernelGGL(partial_k, dim3(nb_scan), dim3(256), 0, stream, cnt, bsum, N);
        hipLaunchKernelGGL(scanb_k, dim3(1), dim3(256), 0, stream, bsum, boff, rowptr, nb_scan, N);
        hipLaunchKernelGGL(rowfill_k, dim3(nb_scan), dim3(256), 0, stream, cnt, boff, rowptr, cursor, N);
        hipLaunchKernelGGL(fill_k, dim3(eb), dim3(256), 0, stream, src, dst, ew, cursor, adj, E);
    }

    int nb = (N * 64 + 255) / 256;
    int nstrips = (N + 15) / 16;
    int mb = (nstrips + 3) / 4;

    hipLaunchKernelGGL(agg_k<0>, dim3(nb), dim3(256), 0, stream, xb, rowptr, adj, aggb, sumew, N);
    hipLaunchKernelGGL(mm1_k, dim3(mb), dim3(256), 0, stream,
                       (const ushort*)aggb, (const ushort*)Wt1, bl1, sumew, rowptr, x1b, N);
    hipLaunchKernelGGL(agg_k<1>, dim3(nb), dim3(256), 0, stream, (const uint*)x1b, rowptr, adj, aggb, sumew, N);
    hipLaunchKernelGGL(mm2_k, dim3(mb), dim3(256), 0, stream,
                       (const ushort*)aggb, (const ushort*)Wt2, bl2, sumew, rowptr, x1b, gamma, beta, out, N);
}

// Round 8
// 167.765 us; speedup vs baseline: 4.0888x; 1.0136x over previous
//
#include <hip/hip_runtime.h>
#include <math.h>

#define DF 128
#define NPB 256   // nodes per bucket (partition path)
#define EPB 4096  // edges per passA/hist block
#define CAP 7168  // passB LDS image capacity (edges)

typedef __attribute__((ext_vector_type(8))) short bf16x8;
typedef __attribute__((ext_vector_type(4))) float f32x4;

__device__ __forceinline__ float bf2f(uint u) {
    union { uint i; float f; } v; v.i = u << 16; return v.f;
}
__device__ __forceinline__ uint f2bf(float f) {  // round-to-nearest-even
    union { float f; uint i; } v; v.f = f;
    return (v.i + 0x7fffu + ((v.i >> 16) & 1u)) >> 16;
}

// ---- fused prep: cvt_x (float4) + cvtW + per-block bucket hist (no atomics, no memset) ----

__global__ void prep_k(const float* __restrict__ x, uint* __restrict__ xb, int n4,
                       const float* __restrict__ W1, const float* __restrict__ W2,
                       uint* __restrict__ Wt1, uint* __restrict__ Wt2,
                       const int* __restrict__ dst, int* __restrict__ bhist, int E,
                       int cvtxB) {
    __shared__ int lh[256];
    int b = blockIdx.x;
    int t = threadIdx.x;
    if (b < cvtxB) {
        int i = b * 256 + t;
        if (i < n4) {
            float4 v = ((const float4*)x)[i];
            uint2 o;
            o.x = f2bf(v.x) | (f2bf(v.y) << 16);
            o.y = f2bf(v.z) | (f2bf(v.w) << 16);
            ((uint2*)xb)[i] = o;
        }
    } else if (b < cvtxB + 64) {
        int i = (b - cvtxB) * 256 + t;  // 0..16383
        const float* W = (i < 8192) ? W1 : W2;
        uint* Wt = (i < 8192) ? Wt1 : Wt2;
        int j = i & 8191;
        int n = j >> 6, kk = j & 63;
        Wt[n * 64 + kk] = f2bf(W[(2 * kk) * DF + n]) | (f2bf(W[(2 * kk + 1) * DF + n]) << 16);
    } else {
        // bucket-level histogram: EPB edges per block, LDS bins, streamed out per-block
        int hb = b - cvtxB - 64;
        int base = hb * EPB;
        lh[t] = 0;
        __syncthreads();
#pragma unroll
        for (int k = 0; k < EPB / 256; ++k) {
            int i = base + k * 256 + t;
            if (i < E) atomicAdd(&lh[dst[i] >> 8], 1);
        }
        __syncthreads();
        bhist[hb * 256 + t] = lh[t];
    }
}

// single block: reduce per-block hists + exclusive scan -> bkoff[257], init gcur
__global__ void bscan_k(const int* __restrict__ bhist, int histB,
                        int* __restrict__ bkoff, int* __restrict__ gcur) {
    int t = threadIdx.x;
    int v = 0;
#pragma unroll 4
    for (int hb = 0; hb < histB; ++hb) v += bhist[hb * 256 + t];
    __shared__ int sm[256];
    sm[t] = v;
    __syncthreads();
    for (int off = 1; off < 256; off <<= 1) {
        int u = (t >= off) ? sm[t - off] : 0;
        __syncthreads();
        sm[t] += u;
        __syncthreads();
    }
    int ex = sm[t] - v;
    bkoff[t] = ex;
    gcur[t] = ex;
    if (t == 255) bkoff[256] = sm[255];
}

// ---------------- partitioned CSR fill ----------------
// Pass A: block-local counting sort of a 4096-edge chunk by dst bucket, write
// per-bucket runs into staging (bucket-major layout). ~21-edge (168B) runs.
__global__ __launch_bounds__(256) void passA_k(
    const int* __restrict__ src, const int* __restrict__ dst,
    const float* __restrict__ ew, int* __restrict__ gcur,
    uint2* __restrict__ stage, int E) {
    __shared__ int lhist[256];
    __shared__ int lscan[256];
    __shared__ int lcur[256];
    __shared__ int gbase[256];
    __shared__ unsigned char lbk[EPB];
    __shared__ uint2 img[EPB];
    int t = threadIdx.x;
    int base = blockIdx.x * EPB;
    int cnt = min(EPB, E - base);
    lhist[t] = 0;
    __syncthreads();
    uint ps[16], pw[16];
    int pb[16];
#pragma unroll
    for (int k = 0; k < 16; ++k) {
        int i = base + k * 256 + t;
        pb[k] = -1;
        if (i < E) {
            int d = dst[i];
            int bk = d >> 8;  // NPB=256
            pb[k] = bk;
            ps[k] = (uint)src[i] | ((uint)(d & 255) << 23);
            pw[k] = __float_as_uint(ew[i]);
            atomicAdd(&lhist[bk], 1);
        }
    }
    __syncthreads();
    int v = lhist[t];
    lscan[t] = v;
    __syncthreads();
    for (int off = 1; off < 256; off <<= 1) {
        int u = (t >= off) ? lscan[t - off] : 0;
        __syncthreads();
        lscan[t] += u;
        __syncthreads();
    }
    lcur[t] = lscan[t] - v;  // exclusive prefix
    if (v > 0) gbase[t] = atomicAdd(&gcur[t], v);
    __syncthreads();
#pragma unroll
    for (int k = 0; k < 16; ++k) {
        if (pb[k] >= 0) {
            int p = atomicAdd(&lcur[pb[k]], 1);
            img[p] = make_uint2(ps[k], pw[k]);
            lbk[p] = (unsigned char)pb[k];
        }
    }
    __syncthreads();
    for (int i = t; i < cnt; i += 256) {
        int bk = lbk[i];
        stage[gbase[bk] + (i - (lscan[bk] - lhist[bk]))] = img[i];
    }
}

// Pass B: one block per bucket. Builds the node-level CSR locally (LDS
// histogram + scan -> rowptr), scatters staged edges into an LDS image,
// copies out coalesced.
__global__ __launch_bounds__(256) void passB_k(
    const uint2* __restrict__ stage, const int* __restrict__ bkoff,
    int* __restrict__ rowptr, int* __restrict__ cursor,
    int2* __restrict__ adj, int N, int nbk) {
    __shared__ int lhist[256];
    __shared__ int lpre[256];
    __shared__ int lcur[256];
    __shared__ uint2 img[CAP];
    int t = threadIdx.x;
    int b = blockIdx.x;
    int nb0 = b * NPB;
    int nn = min(NPB, N - nb0);
    int ebase = bkoff[b];
    int ecnt = bkoff[b + 1] - ebase;
    lhist[t] = 0;
    __syncthreads();
    for (int i = t; i < ecnt; i += 256) {
        uint2 e = stage[ebase + i];
        atomicAdd(&lhist[(e.x >> 23) & 255], 1);
    }
    __syncthreads();
    int v = lhist[t];
    lpre[t] = v;
    __syncthreads();
    for (int off = 1; off < 256; off <<= 1) {
        int u = (t >= off) ? lpre[t - off] : 0;
        __syncthreads();
        lpre[t] += u;
        __syncthreads();
    }
    int myoff = lpre[t] - v;  // exclusive prefix within bucket
    lcur[t] = myoff;
    if (t < nn) {
        rowptr[nb0 + t] = ebase + myoff;
        cursor[nb0 + t] = ebase + myoff;
    }
    if (b == nbk - 1 && t == 0) rowptr[N] = ebase + ecnt;
    __syncthreads();
    if (ecnt <= CAP) {
        for (int i = t; i < ecnt; i += 256) {
            uint2 e = stage[ebase + i];
            int p = atomicAdd(&lcur[(e.x >> 23) & 255], 1);
            img[p] = make_uint2(e.x & 0x7fffffu, e.y);
        }
        __syncthreads();
        for (int i = t; i < ecnt; i += 256) {
            uint2 e = img[i];
            adj[ebase + i] = make_int2((int)e.x, (int)e.y);
        }
    } else {  // statistically unreachable; correctness fallback
        for (int i = t; i < ecnt; i += 256) {
            uint2 e = stage[ebase + i];
            int dl = (e.x >> 23) & 255;
            int p = atomicAdd(&cursor[nb0 + dl], 1);
            adj[p] = make_int2((int)(e.x & 0x7fffffu), (int)e.y);
        }
    }
}

// ---------------- generic fallback path (N > 65536 only) ----------------

__global__ void histn_k(const int* __restrict__ dst, int* __restrict__ cnt, int E) {
    int i = blockIdx.x * blockDim.x + threadIdx.x;
    if (i < E) atomicAdd(&cnt[dst[i]], 1);
}

__global__ void partial_k(const int* __restrict__ cnt, int* __restrict__ bsum, int N) {
    int t = threadIdx.x, b = blockIdx.x;
    int base = b * 1024 + t * 4;
    int s = 0;
    if (base + 4 <= N) {
        int4 v = *(const int4*)(cnt + base);
        s = v.x + v.y + v.z + v.w;
    } else {
        for (int j = 0; j < 4; ++j)
            if (base + j < N) s += cnt[base + j];
    }
    __shared__ int sm[256];
    sm[t] = s;
    __syncthreads();
    for (int off = 128; off > 0; off >>= 1) {
        if (t < off) sm[t] += sm[t + off];
        __syncthreads();
    }
    if (t == 0) bsum[b] = sm[0];
}

__global__ void scanb_k(const int* __restrict__ bsum, int* __restrict__ boff,
                        int* __restrict__ rowptr, int nb, int N) {
    int t = threadIdx.x;
    int v = (t < nb) ? bsum[t] : 0;
    __shared__ int sm[256];
    sm[t] = v;
    __syncthreads();
    for (int off = 1; off < 256; off <<= 1) {
        int u = (t >= off) ? sm[t - off] : 0;
        __syncthreads();
        sm[t] += u;
        __syncthreads();
    }
    if (t < nb) boff[t] = sm[t] - v;
    if (t == 255) rowptr[N] = sm[255];
}

__global__ void rowfill_k(const int* __restrict__ cnt, const int* __restrict__ boff,
                          int* __restrict__ rowptr, int* __restrict__ cursor, int N) {
    int t = threadIdx.x, b = blockIdx.x;
    int base = b * 1024 + t * 4;
    int c0 = 0, c1 = 0, c2 = 0, c3 = 0;
    if (base + 4 <= N) {
        int4 v = *(const int4*)(cnt + base);
        c0 = v.x; c1 = v.y; c2 = v.z; c3 = v.w;
    } else {
        if (base + 0 < N) c0 = cnt[base + 0];
        if (base + 1 < N) c1 = cnt[base + 1];
        if (base + 2 < N) c2 = cnt[base + 2];
        if (base + 3 < N) c3 = cnt[base + 3];
    }
    int s = c0 + c1 + c2 + c3;
    __shared__ int sm[256];
    sm[t] = s;
    __syncthreads();
    for (int off = 1; off < 256; off <<= 1) {
        int u = (t >= off) ? sm[t - off] : 0;
        __syncthreads();
        sm[t] += u;
        __syncthreads();
    }
    int run = boff[b] + sm[t] - s;
    if (base + 0 < N) { rowptr[base + 0] = run; cursor[base + 0] = run; run += c0; }
    if (base + 1 < N) { rowptr[base + 1] = run; cursor[base + 1] = run; run += c1; }
    if (base + 2 < N) { rowptr[base + 2] = run; cursor[base + 2] = run; run += c2; }
    if (base + 3 < N) { rowptr[base + 3] = run; cursor[base + 3] = run; run += c3; }
}

__global__ void fill_k(const int* __restrict__ src, const int* __restrict__ dst,
                       const float* __restrict__ ew, int* __restrict__ cursor,
                       int2* __restrict__ adj, int E) {
    int i = blockIdx.x * blockDim.x + threadIdx.x;
    if (i < E) {
        int p = atomicAdd(&cursor[dst[i]], 1);
        int2 e;
        e.x = src[i];
        e.y = __float_as_int(ew[i]);
        adj[p] = e;
    }
}

// ---- aggregation: one wave per node, 2 rows per gather (uint2/lane, half-waves) ----

template <int SELF>
__global__ void agg_k(const uint2* __restrict__ xb2, const int* __restrict__ rowptr,
                      const int2* __restrict__ adj, uint2* __restrict__ aggb2,
                      float* __restrict__ sumew, int N) {
    int wid = (blockIdx.x * blockDim.x + threadIdx.x) >> 6;
    int lane = threadIdx.x & 63;
    if (wid >= N) return;
    int half = lane >> 5;   // 0: even edges, 1: odd edges
    int sl = lane & 31;     // column quad (4 bf16 per lane)
    int lo = rowptr[wid], hi = rowptr[wid + 1];
    float a0 = 0.f, a1 = 0.f, a2 = 0.f, a3 = 0.f, ws = 0.f;
    if (SELF && half == 0) {
        uint2 v = xb2[(size_t)wid * 32 + sl];
        a0 = bf2f(v.x & 0xffffu); a1 = bf2f(v.x >> 16);
        a2 = bf2f(v.y & 0xffffu); a3 = bf2f(v.y >> 16);
    }
    for (int base = lo; base < hi; base += 64) {
        int p = base + lane;
        int sidx = 0; float wv = 0.f;
        if (p < hi) {
            int2 e = adj[p];
            sidx = e.x;
            wv = __int_as_float(e.y);
        }
        ws += wv;
        int cnt = min(hi - base, 64);
        int j = 0;
        for (; j + 8 <= cnt; j += 8) {  // 4 row-pairs in flight
            int s0 = __shfl(sidx, j + half),     s1 = __shfl(sidx, j + 2 + half);
            int s2 = __shfl(sidx, j + 4 + half), s3 = __shfl(sidx, j + 6 + half);
            float w0 = __shfl(wv, j + half),     w1 = __shfl(wv, j + 2 + half);
            float w2 = __shfl(wv, j + 4 + half), w3 = __shfl(wv, j + 6 + half);
            uint2 v0 = xb2[(size_t)s0 * 32 + sl];
            uint2 v1 = xb2[(size_t)s1 * 32 + sl];
            uint2 v2 = xb2[(size_t)s2 * 32 + sl];
            uint2 v3 = xb2[(size_t)s3 * 32 + sl];
            a0 += w0 * bf2f(v0.x & 0xffffu); a1 += w0 * bf2f(v0.x >> 16);
            a2 += w0 * bf2f(v0.y & 0xffffu); a3 += w0 * bf2f(v0.y >> 16);
            a0 += w1 * bf2f(v1.x & 0xffffu); a1 += w1 * bf2f(v1.x >> 16);
            a2 += w1 * bf2f(v1.y & 0xffffu); a3 += w1 * bf2f(v1.y >> 16);
            a0 += w2 * bf2f(v2.x & 0xffffu); a1 += w2 * bf2f(v2.x >> 16);
            a2 += w2 * bf2f(v2.y & 0xffffu); a3 += w2 * bf2f(v2.y >> 16);
            a0 += w3 * bf2f(v3.x & 0xffffu); a1 += w3 * bf2f(v3.x >> 16);
            a2 += w3 * bf2f(v3.y & 0xffffu); a3 += w3 * bf2f(v3.y >> 16);
        }
        for (; j < cnt; j += 2) {
            // phantom odd-tail edge has sidx=0, wv=0 -> harmless
            int s0 = __shfl(sidx, j + half);
            float w0 = __shfl(wv, j + half);
            uint2 v0 = xb2[(size_t)s0 * 32 + sl];
            a0 += w0 * bf2f(v0.x & 0xffffu); a1 += w0 * bf2f(v0.x >> 16);
            a2 += w0 * bf2f(v0.y & 0xffffu); a3 += w0 * bf2f(v0.y >> 16);
        }
    }
    // combine half-waves
    a0 += __shfl_xor(a0, 32);
    a1 += __shfl_xor(a1, 32);
    a2 += __shfl_xor(a2, 32);
    a3 += __shfl_xor(a3, 32);
    if (!SELF) {
        ws += __shfl_xor(ws, 1);
        ws += __shfl_xor(ws, 2);
        ws += __shfl_xor(ws, 4);
        ws += __shfl_xor(ws, 8);
        ws += __shfl_xor(ws, 16);
        ws += __shfl_xor(ws, 32);
        if (lane == 0) sumew[wid] = ws;
    }
    float inv = SELF ? 1.0f / (float)(hi - lo + 1)
                     : 1.0f / fmaxf((float)(hi - lo), 1.0f);
    if (half == 0) {
        uint2 o;
        o.x = f2bf(a0 * inv) | (f2bf(a1 * inv) << 16);
        o.y = f2bf(a2 * inv) | (f2bf(a3 * inv) << 16);
        aggb2[(size_t)wid * 32 + sl] = o;
    }
}

// ---------------- MFMA GEMMs: one wave per 16-row strip ----------------
// A frag: row=lane&15, k=(lane>>4)*8+j ; B frag: col=lane&15, same k
// D: col=lane&15, row=(lane>>4)*4+reg   [m89-verified]

__global__ __launch_bounds__(256) void mm1_k(
    const ushort* __restrict__ aggb, const ushort* __restrict__ Wt,
    const float* __restrict__ bl, const float* __restrict__ sumew,
    const int* __restrict__ rowptr, ushort* __restrict__ x1b, int N) {
    int lane = threadIdx.x & 63;
    int strip = blockIdx.x * 4 + (threadIdx.x >> 6);
    int nstrips = (N + 15) >> 4;
    if (strip >= nstrips) return;
    int row0 = strip << 4;
    int arow = row0 + (lane & 15);
    if (arow >= N) arow = N - 1;
    int kg = (lane >> 4) << 3;
    int bcol = lane & 15;

    bf16x8 af[4];
#pragma unroll
    for (int kc = 0; kc < 4; ++kc)
        af[kc] = *(const bf16x8*)(aggb + (size_t)arow * DF + kc * 32 + kg);

    f32x4 acc[8];
#pragma unroll
    for (int nt = 0; nt < 8; ++nt) {
        f32x4 a = {0.f, 0.f, 0.f, 0.f};
#pragma unroll
        for (int kc = 0; kc < 4; ++kc) {
            bf16x8 bf = *(const bf16x8*)(Wt + (size_t)(nt * 16 + bcol) * DF + kc * 32 + kg);
            a = __builtin_amdgcn_mfma_f32_16x16x32_bf16(af[kc], bf, a, 0, 0, 0);
        }
        acc[nt] = a;
    }

#pragma unroll
    for (int r = 0; r < 4; ++r) {
        int R = row0 + ((lane >> 4) << 2) + r;
        if (R >= N) continue;
        int deg = rowptr[R + 1] - rowptr[R];
        float wb = sumew[R] / fmaxf((float)deg, 1.0f);
#pragma unroll
        for (int nt = 0; nt < 8; ++nt) {
            int col = nt * 16 + bcol;
            x1b[(size_t)R * DF + col] = (ushort)f2bf(acc[nt][r] + bl[col] * wb);
        }
    }
}

__device__ __forceinline__ float gelu_exact(float v) {
    return 0.5f * v * (1.0f + erff(v * 0.70710678118654752440f));
}

__global__ __launch_bounds__(256) void mm2_k(
    const ushort* __restrict__ aggb, const ushort* __restrict__ Wt,
    const float* __restrict__ bl, const float* __restrict__ sumew,
    const int* __restrict__ rowptr, const ushort* __restrict__ x1b,
    const float* __restrict__ gamma, const float* __restrict__ beta,
    float* __restrict__ out, int N) {
    int lane = threadIdx.x & 63;
    int strip = blockIdx.x * 4 + (threadIdx.x >> 6);
    int nstrips = (N + 15) >> 4;
    if (strip >= nstrips) return;
    int row0 = strip << 4;
    int arow = row0 + (lane & 15);
    if (arow >= N) arow = N - 1;
    int kg = (lane >> 4) << 3;
    int bcol = lane & 15;

    bf16x8 af[4];
#pragma unroll
    for (int kc = 0; kc < 4; ++kc)
        af[kc] = *(const bf16x8*)(aggb + (size_t)arow * DF + kc * 32 + kg);

    f32x4 acc[8];
#pragma unroll
    for (int nt = 0; nt < 8; ++nt) {
        f32x4 a = {0.f, 0.f, 0.f, 0.f};
#pragma unroll
        for (int kc = 0; kc < 4; ++kc) {
            bf16x8 bf = *(const bf16x8*)(Wt + (size_t)(nt * 16 + bcol) * DF + kc * 32 + kg);
            a = __builtin_amdgcn_mfma_f32_16x16x32_bf16(af[kc], bf, a, 0, 0, 0);
        }
        acc[nt] = a;
    }

#pragma unroll
    for (int r = 0; r < 4; ++r) {
        int R = row0 + ((lane >> 4) << 2) + r;
        if (R >= N) continue;
        int deg = rowptr[R + 1] - rowptr[R];
        float wb = (sumew[R] + 1.0f) / (float)(deg + 1);
        float pre[8];
        float s = 0.f;
#pragma unroll
        for (int nt = 0; nt < 8; ++nt) {
            int col = nt * 16 + bcol;
            pre[nt] = acc[nt][r] + bl[col] * wb + bf2f(x1b[(size_t)R * DF + col]);
            s += pre[nt];
        }
        s += __shfl_xor(s, 1);
        s += __shfl_xor(s, 2);
        s += __shfl_xor(s, 4);
        s += __shfl_xor(s, 8);
        float mu = s * (1.0f / 128.0f);
        float vs = 0.f;
#pragma unroll
        for (int nt = 0; nt < 8; ++nt) {
            float d = pre[nt] - mu;
            vs += d * d;
        }
        vs += __shfl_xor(vs, 1);
        vs += __shfl_xor(vs, 2);
        vs += __shfl_xor(vs, 4);
        vs += __shfl_xor(vs, 8);
        float rstd = rsqrtf(vs * (1.0f / 128.0f) + 1e-5f);
#pragma unroll
        for (int nt = 0; nt < 8; ++nt) {
            int col = nt * 16 + bcol;
            float y = (pre[nt] - mu) * rstd * gamma[col] + beta[col];
            out[(size_t)R * DF + col] = gelu_exact(y);
        }
    }
}

// ---------------- launch ----------------

extern "C" void kernel_launch(void* const* d_in, const int* in_sizes, int n_in,
                              void* d_out, int out_size, void* d_ws, size_t ws_size,
                              hipStream_t stream) {
    const float* x     = (const float*)d_in[0];
    const int*   ei    = (const int*)d_in[1];
    const float* ew    = (const float*)d_in[2];
    const float* Wl1   = (const float*)d_in[3];
    const float* bl1   = (const float*)d_in[4];
    const float* Wl2   = (const float*)d_in[5];
    const float* bl2   = (const float*)d_in[6];
    const float* gamma = (const float*)d_in[7];
    const float* beta  = (const float*)d_in[8];
    float* out = (float*)d_out;

    int N = in_sizes[0] / DF;
    int E = in_sizes[2];
    const int* src = ei;
    const int* dst = ei + E;

    char* ws = (char*)d_ws;
    size_t off = 0;
    auto alloc = [&](size_t bytes) -> void* {
        void* p = ws + off;
        off += (bytes + 255) & ~(size_t)255;
        return p;
    };
    int histB = (E + EPB - 1) / EPB;
    float*  sumew   = (float*)alloc((size_t)N * 4);
    int*    rowptr  = (int*)alloc((size_t)(N + 1) * 4);
    int*    cursor  = (int*)alloc((size_t)N * 4);
    int*    bhist   = (int*)alloc((size_t)histB * 256 * 4);
    int*    bkoff   = (int*)alloc(1040);
    int*    gcur    = (int*)alloc(1024);
    int*    bsum    = (int*)alloc(1024);
    int*    boff    = (int*)alloc(1024);
    int2*   adj     = (int2*)alloc((size_t)E * 8);
    uint2*  stage   = (uint2*)alloc((size_t)E * 8);
    uint*   xb      = (uint*)alloc((size_t)N * DF * 2);
    uint*   aggb    = (uint*)alloc((size_t)N * DF * 2);
    ushort* x1b     = (ushort*)alloc((size_t)N * DF * 2);
    uint*   Wt1     = (uint*)alloc((size_t)DF * DF * 2);
    uint*   Wt2     = (uint*)alloc((size_t)DF * DF * 2);
    int*    cnt     = (int*)alloc((size_t)N * 4);  // fallback path only

    int nbk = (N + NPB - 1) / NPB;
    int n4 = N * DF / 4;
    int cvtxB = (n4 + 255) / 256;

    if (nbk <= 256) {
        hipLaunchKernelGGL(prep_k, dim3(cvtxB + 64 + histB), dim3(256), 0, stream,
                           x, xb, n4, Wl1, Wl2, Wt1, Wt2, dst, bhist, E, cvtxB);
        hipLaunchKernelGGL(bscan_k, dim3(1), dim3(256), 0, stream, bhist, histB, bkoff, gcur);
        hipLaunchKernelGGL(passA_k, dim3(histB), dim3(256), 0, stream, src, dst, ew, gcur, stage, E);
        hipLaunchKernelGGL(passB_k, dim3(nbk), dim3(256), 0, stream,
                           stage, bkoff, rowptr, cursor, adj, N, nbk);
    } else {  // generic fallback (not taken for this problem size)
        hipMemsetAsync(cnt, 0, (size_t)N * 4, stream);
        hipLaunchKernelGGL(prep_k, dim3(cvtxB + 64), dim3(256), 0, stream,
                           x, xb, n4, Wl1, Wl2, Wt1, Wt2, dst, bhist, 0, cvtxB);
        int eb = (E + 255) / 256;
        hipLaunchKernelGGL(histn_k, dim3(eb), dim3(256), 0, stream, dst, cnt, E);
        int nb_scan = (N + 1023) / 1024;
        hipLaunchKernelGGL(partial_k, dim3(nb_scan), dim3(256), 0, stream, cnt, bsum, N);
        hipLaunchKernelGGL(scanb_k, dim3(1), dim3(256), 0, stream, bsum, boff, rowptr, nb_scan, N);
        hipLaunchKernelGGL(rowfill_k, dim3(nb_scan), dim3(256), 0, stream, cnt, boff, rowptr, cursor, N);
        hipLaunchKernelGGL(fill_k, dim3(eb), dim3(256), 0, stream, src, dst, ew, cursor, adj, E);
    }

    int nb = (N * 64 + 255) / 256;
    int nstrips = (N + 15) / 16;
    int mb = (nstrips + 3) / 4;

    hipLaunchKernelGGL(agg_k<0>, dim3(nb), dim3(256), 0, stream,
                       (const uint2*)xb, rowptr, adj, (uint2*)aggb, sumew, N);
    hipLaunchKernelGGL(mm1_k, dim3(mb), dim3(256), 0, stream,
                       (const ushort*)aggb, (const ushort*)Wt1, bl1, sumew, rowptr, x1b, N);
    hipLaunchKernelGGL(agg_k<1>, dim3(nb), dim3(256), 0, stream,
                       (const uint2*)x1b, rowptr, adj, (uint2*)aggb, sumew, N);
    hipLaunchKernelGGL(mm2_k, dim3(mb), dim3(256), 0, stream,
                       (const ushort*)aggb, (const ushort*)Wt2, bl2, sumew, rowptr, x1b, gamma, beta, out, N);
}